// Round 7
// baseline (320.352 us; speedup 1.0000x reference)
//
#include <hip/hip_runtime.h>
#include <cmath>

#define LL 2048
#define NROW 8192
#define DMODEL 1024
#define DINNER 2048
#define NSTATE 16
#define NSEG 64
#define SEGLEN 32   // NSEG * SEGLEN == LL

typedef unsigned short u16;
typedef __attribute__((ext_vector_type(8))) unsigned short u16x8;
typedef __attribute__((ext_vector_type(8))) short short8;
typedef __attribute__((ext_vector_type(4))) float floatx4;
typedef __attribute__((ext_vector_type(16))) float floatx16;

__device__ __forceinline__ float bf2f(u16 h) {
    unsigned u = ((unsigned)h) << 16;
    float f;
    __builtin_memcpy(&f, &u, 4);
    return f;
}
__device__ __forceinline__ u16 f2bf(float f) {
    unsigned u;
    __builtin_memcpy(&u, &f, 4);
    u = u + 0x7fffu + ((u >> 16) & 1u);
    return (u16)(u >> 16);
}
__device__ __forceinline__ float silu_f(float x) { return x / (1.f + __expf(-x)); }

// One kernel converts all six fp32->bf16 tensors (2048 elems per block).
__global__ __launch_bounds__(256) void cvt_multi(
    const float* __restrict__ s0, const float* __restrict__ s1,
    const float* __restrict__ s2, const float* __restrict__ s3,
    const float* __restrict__ s4, const float* __restrict__ s5,
    u16* __restrict__ d0, u16* __restrict__ d1, u16* __restrict__ d2,
    u16* __restrict__ d3, u16* __restrict__ d4, u16* __restrict__ d5) {
    int bid = blockIdx.x;
    const float* s;
    u16* d;
    size_t off;
    if (bid < 4096)      { s = s0; d = d0; off = (size_t)bid * 2048; }
    else if (bid < 6144) { s = s1; d = d1; off = (size_t)(bid - 4096) * 2048; }
    else if (bid < 7168) { s = s2; d = d2; off = (size_t)(bid - 6144) * 2048; }
    else if (bid < 7184) { s = s3; d = d3; off = (size_t)(bid - 7168) * 2048; }
    else if (bid < 7200) { s = s4; d = d4; off = (size_t)(bid - 7184) * 2048; }
    else                 { s = s5; d = d5; off = (size_t)(bid - 7200) * 2048; }
    size_t i = off + (size_t)threadIdx.x * 8;
    float4 a = *(const float4*)&s[i];
    float4 b = *(const float4*)&s[i + 4];
    u16x8 o;
    o[0] = f2bf(a.x); o[1] = f2bf(a.y); o[2] = f2bf(a.z); o[3] = f2bf(a.w);
    o[4] = f2bf(b.x); o[5] = f2bf(b.y); o[6] = f2bf(b.z); o[7] = f2bf(b.w);
    *(u16x8*)&d[i] = o;
}

#define GL_LDS(gp, lp)                                                        \
    __builtin_amdgcn_global_load_lds(                                         \
        (const __attribute__((address_space(1))) void*)(gp),                  \
        (__attribute__((address_space(3))) void*)(lp), 16, 0, 0)
#define BAR() __builtin_amdgcn_s_barrier()
#define SB0() __builtin_amdgcn_sched_barrier(0)
#define LGKM0()                                                               \
    do {                                                                      \
        asm volatile("s_waitcnt lgkmcnt(0)" ::: "memory");                    \
        __builtin_amdgcn_sched_barrier(0);                                    \
    } while (0)
#define VMC8() asm volatile("s_waitcnt vmcnt(8)" ::: "memory")
#define VMC4() asm volatile("s_waitcnt vmcnt(4)" ::: "memory")
#define VMC2() asm volatile("s_waitcnt vmcnt(2)" ::: "memory")
#define PRIO1() __builtin_amdgcn_s_setprio(1)
#define PRIO0() __builtin_amdgcn_s_setprio(0)

// ---------------------------------------------------------------------------
// 256x256 GEMM (C = A @ B^T), hoisted-reads pipelined schedule (R7).
// Same LDS layout / swizzle / fragment maps / register sets as the
// R4-verified kernel (73.5 us, 0 conflicts); only instruction order and
// the staging train changed.
// Per K-tile (BK=64), cur = t&1:
//  ph1: lgkm0 (drains afX,bf01 read at prev tile end -- the one exposed
//       wait/tile); issue RD bf23+afY (cur); MFMA(afX,bf01)
//  ph2: lgkm0 (covered by ph1 MFMA); MFMA(afX,bf23); BARRIER
//       [WAR gate: every wave's cur-buffer ds_reads are drained]
//  ph3: MFMA(afY,bf01); stage A0,A1,B0 of tile t+2 -> cur buffers
//  ph4: MFMA(afY,bf23); stage B1(t+2); vmcnt(8) [8 newest = t+2 stages =>
//       A(t+1),B(t+1) landed]; BARRIER; read afX,bf01 from nxt buffer.
// 2 barriers + 1 vmcnt per tile; never vmcnt(0) in the loop. Both A and B
// staged 2 tiles ahead (legal: cur-buffer reads drained at ph2 barrier).
// Prologue stages tiles 0,1 (16 loads); vmcnt(8) = tile-0 landed.
// Staging pointers overrun K-end by <=2 tiles into the adjacent workspace
// allocation (callers: xb->wb, wb->owb readable).
// XCD-aware bijective block swizzle (grid % 8 == 0).
// ---------------------------------------------------------------------------
template <int OUT_BF16>
__global__ __launch_bounds__(512, 2) void gemm_bt_256(
    const u16* __restrict__ A, const u16* __restrict__ B,
    void* __restrict__ Cout, int N, int K) {
    __shared__ u16 sAf[2 * 2 * 128 * 64];   // [buf][half][row*64 + slot*8]
    __shared__ u16 sBf[2 * 2 * 128 * 64];
    const int tid = threadIdx.x;
    const int lane = tid & 63;
    const int wave = tid >> 6;   // 0..7
    const int wm = wave >> 2;    // 0..1
    const int wn = wave & 3;     // 0..3

    // XCD swizzle: linearize grid, chunk per XCD (nwg % 8 == 0 here).
    const int gx = gridDim.x;
    const int nwg = gx * gridDim.y;
    const int cpx = nwg >> 3;
    int lin = blockIdx.y * gx + blockIdx.x;
    int swz = (lin & 7) * cpx + (lin >> 3);
    const int bm = (swz / gx) * 256;
    const int bn = (swz % gx) * 256;

    // ---- staging addresses (pre-swizzled source k-slot) ----
    const int gslot = (lane & 7) ^ ((lane >> 3) & 7);
    const int srowoff = lane >> 3;                  // 0..7
    // stage pointers track tile t+2 (k-offset +128)
    const u16* aStage = A + (size_t)(bm + wave * 8 + srowoff) * K + gslot * 8 + 128;
    const u16* bStage = B + (size_t)(bn + wave * 8 + srowoff) * K + gslot * 8 + 128;
    const size_t row64 = (size_t)64 * K;
    const size_t row128 = (size_t)128 * K;

#define STAGE_A(BUF, H, PTR)                                                  \
    do {                                                                      \
        GL_LDS((PTR) + (H) * row128,         &sAf[(BUF) * 16384 + (H) * 8192 + wave * 512]); \
        GL_LDS((PTR) + (H) * row128 + row64, &sAf[(BUF) * 16384 + (H) * 8192 + (8 + wave) * 512]); \
    } while (0)
#define STAGE_B(BUF, H, PTR)                                                  \
    do {                                                                      \
        GL_LDS((PTR) + (H) * row128,         &sBf[(BUF) * 16384 + (H) * 8192 + wave * 512]); \
        GL_LDS((PTR) + (H) * row128 + row64, &sBf[(BUF) * 16384 + (H) * 8192 + (8 + wave) * 512]); \
    } while (0)

    // ---- fragment read bases (element offsets) ----
    const int fr = lane & 15;
    const int kq = lane >> 4;
    const int st0 = kq ^ (fr & 7);
    const int st1 = (4 + kq) ^ (fr & 7);
    const int aRd0 = wm * 8192 + fr * 64 + st0 * 8;
    const int aRd1 = wm * 8192 + fr * 64 + st1 * 8;
    const int bRow = (wn & 1) * 64 + fr;
    const int bRd0 = (wn >> 1) * 8192 + bRow * 64 + st0 * 8;
    const int bRd1 = (wn >> 1) * 8192 + bRow * 64 + st1 * 8;

#define RD_A(dst, BUF, R0)                                                    \
    do {                                                                      \
        _Pragma("unroll")                                                     \
        for (int mi = 0; mi < 4; ++mi) {                                      \
            dst[mi][0] = *(const short8*)&sAf[(BUF) * 16384 + aRd0 + ((R0) + mi * 16) * 64]; \
            dst[mi][1] = *(const short8*)&sAf[(BUF) * 16384 + aRd1 + ((R0) + mi * 16) * 64]; \
        }                                                                     \
    } while (0)
#define RD_B(dst, BUF, R0)                                                    \
    do {                                                                      \
        _Pragma("unroll")                                                     \
        for (int ni = 0; ni < 2; ++ni) {                                      \
            dst[ni][0] = *(const short8*)&sBf[(BUF) * 16384 + bRd0 + ((R0) + ni * 16) * 64]; \
            dst[ni][1] = *(const short8*)&sBf[(BUF) * 16384 + bRd1 + ((R0) + ni * 16) * 64]; \
        }                                                                     \
    } while (0)
#define MFMA_PH(AF, RB, BF, CB)                                               \
    do {                                                                      \
        _Pragma("unroll")                                                     \
        for (int kh = 0; kh < 2; ++kh)                                        \
            _Pragma("unroll")                                                 \
            for (int mi = 0; mi < 4; ++mi)                                    \
                _Pragma("unroll")                                             \
                for (int ni = 0; ni < 2; ++ni)                                \
                    acc[(RB) + mi][(CB) + ni] =                               \
                        __builtin_amdgcn_mfma_f32_16x16x32_bf16(              \
                            AF[mi][kh], BF[ni][kh],                           \
                            acc[(RB) + mi][(CB) + ni], 0, 0, 0);              \
    } while (0)

    floatx4 acc[8][4];
#pragma unroll
    for (int i = 0; i < 8; ++i)
#pragma unroll
        for (int j = 0; j < 4; ++j) acc[i][j] = (floatx4){0.f, 0.f, 0.f, 0.f};

    short8 afX[4][2], afY[4][2], bf01[2][2], bf23[2][2];

    // ---- prologue: stage tiles 0 and 1; vmcnt(8) => tile-0 data landed ----
    {
        const u16* a0 = aStage - 128;
        const u16* b0 = bStage - 128;
        STAGE_A(0, 0, a0);
        STAGE_A(0, 1, a0);
        STAGE_B(0, 0, b0);
        STAGE_B(0, 1, b0);
        STAGE_A(1, 0, a0 + 64);
        STAGE_A(1, 1, a0 + 64);
        STAGE_B(1, 0, b0 + 64);
        STAGE_B(1, 1, b0 + 64);
    }
    VMC8();
    BAR();
    RD_A(afX, 0, 0);
    RD_B(bf01, 0, 0);
    SB0();

// TILE body; CUR/NXT compile-time via x2 unroll.
#define TILE(CUR, NXT)                                                        \
    /* ph1: drain prev-tile-end reads; issue cur's remaining reads; MFMA */   \
    LGKM0();                                                                  \
    RD_B(bf23, CUR, 32);                                                      \
    RD_A(afY, CUR, 64);                                                       \
    SB0();                                                                    \
    PRIO1();                                                                  \
    MFMA_PH(afX, 0, bf01, 0);                                                 \
    PRIO0();                                                                  \
    SB0();                                                                    \
    /* ph2: drain bf23/afY (covered by ph1 MFMA); MFMA; WAR barrier */        \
    LGKM0();                                                                  \
    PRIO1();                                                                  \
    MFMA_PH(afX, 0, bf23, 2);                                                 \
    PRIO0();                                                                  \
    SB0();                                                                    \
    BAR();                                                                    \
    /* ph3: MFMA (regs ready); stage A0,A1,B0 of t+2 into cur */              \
    PRIO1();                                                                  \
    MFMA_PH(afY, 4, bf01, 0);                                                 \
    PRIO0();                                                                  \
    SB0();                                                                    \
    STAGE_A(CUR, 0, aStage);                                                  \
    STAGE_A(CUR, 1, aStage);                                                  \
    STAGE_B(CUR, 0, bStage);                                                  \
    SB0();                                                                    \
    /* ph4: MFMA; stage B1(t+2); vmcnt(8); barrier; read nxt frags */         \
    PRIO1();                                                                  \
    MFMA_PH(afY, 4, bf23, 2);                                                 \
    PRIO0();                                                                  \
    SB0();                                                                    \
    STAGE_B(CUR, 1, bStage);                                                  \
    VMC8(); /* A(t+1),B(t+1) landed; t+2 stages stay in flight */             \
    BAR();                                                                    \
    RD_A(afX, NXT, 0);                                                        \
    RD_B(bf01, NXT, 0);                                                       \
    SB0();                                                                    \
    aStage += 64;                                                             \
    bStage += 64;

    const int NT = K >> 6;  // even (16 here)
    for (int t = 0; t < NT; t += 2) {
        TILE(0, 1)
        TILE(1, 0)
    }
#undef TILE

    // epilogue: C/D 16x16 layout: col = lane&15, row = (lane>>4)*4 + r
    const int cc = lane & 15;
    const int rb = (lane >> 4) * 4;
#pragma unroll
    for (int mi = 0; mi < 8; ++mi)
#pragma unroll
        for (int ni = 0; ni < 4; ++ni)
#pragma unroll
            for (int r = 0; r < 4; ++r) {
                int grow = bm + wm * 128 + mi * 16 + rb + r;
                int gcol = bn + wn * 64 + ni * 16 + cc;
                float v = acc[mi][ni][r];
                if (OUT_BF16)
                    ((u16*)Cout)[(size_t)grow * N + gcol] = f2bf(v);
                else
                    ((float*)Cout)[(size_t)grow * N + gcol] = v;
            }
#undef STAGE_A
#undef STAGE_B
#undef RD_A
#undef RD_B
#undef MFMA_PH
}

// ---------------------------------------------------------------------------
// 128x128 GEMM (C = A @ B^T), pipelined schedule at 128-tile for the thin
// out-proj (N=1024 -> 512 blocks). BK=64, 8 waves (2M x 4N), per-wave C =
// 64x32. LDS 64 KiB dbuf -> 2 blocks/CU (4 waves/SIMD). 2 phases/tile,
// 2 barriers, counted vmcnt(2). (R6-verified.)
// ---------------------------------------------------------------------------
template <int OUT_BF16>
__global__ __launch_bounds__(512, 4) void gemm_bt_128p(
    const u16* __restrict__ A, const u16* __restrict__ B,
    void* __restrict__ Cout, int N, int K) {
    __shared__ u16 sAf[2 * 128 * 64];   // [buf][row*64 + slot*8]
    __shared__ u16 sBf[2 * 128 * 64];
    const int tid = threadIdx.x;
    const int lane = tid & 63;
    const int wave = tid >> 6;   // 0..7
    const int wm = wave >> 2;    // 0..1  (M half: 64 rows)
    const int wn = wave & 3;     // 0..3  (N quarter: 32 cols)

    const int gx = gridDim.x;
    const int nwg = gx * gridDim.y;
    const int cpx = nwg >> 3;                       // nwg % 8 == 0 here
    int lin = blockIdx.y * gx + blockIdx.x;
    int swz = (lin & 7) * cpx + (lin >> 3);
    const int bm = (swz / gx) * 128;
    const int bn = (swz % gx) * 128;

    const int gslot = (lane & 7) ^ ((lane >> 3) & 7);
    const int srowoff = lane >> 3;                  // 0..7
    const u16* aStage = A + (size_t)(bm + wave * 8 + srowoff) * K + gslot * 8 + 64;
    const u16* bStage = B + (size_t)(bn + wave * 8 + srowoff) * K + gslot * 8 + 128;
    const size_t row64 = (size_t)64 * K;

#define STAGE_A(BUF, PTR)                                                     \
    do {                                                                      \
        GL_LDS((PTR),         &sAf[(BUF) * 8192 + wave * 512]);               \
        GL_LDS((PTR) + row64, &sAf[(BUF) * 8192 + (8 + wave) * 512]);         \
    } while (0)
#define STAGE_B(BUF, PTR)                                                     \
    do {                                                                      \
        GL_LDS((PTR),         &sBf[(BUF) * 8192 + wave * 512]);               \
        GL_LDS((PTR) + row64, &sBf[(BUF) * 8192 + (8 + wave) * 512]);         \
    } while (0)

    const int fr = lane & 15;
    const int kq = lane >> 4;
    const int st0 = kq ^ (fr & 7);
    const int st1 = (4 + kq) ^ (fr & 7);
    const int aRd0 = (wm * 64 + fr) * 64 + st0 * 8;
    const int aRd1 = (wm * 64 + fr) * 64 + st1 * 8;
    const int bRd0 = (wn * 32 + fr) * 64 + st0 * 8;
    const int bRd1 = (wn * 32 + fr) * 64 + st1 * 8;

#define RD_A(dst, BUF)                                                        \
    do {                                                                      \
        _Pragma("unroll")                                                     \
        for (int mi = 0; mi < 4; ++mi) {                                      \
            dst[mi][0] = *(const short8*)&sAf[(BUF) * 8192 + aRd0 + mi * 16 * 64]; \
            dst[mi][1] = *(const short8*)&sAf[(BUF) * 8192 + aRd1 + mi * 16 * 64]; \
        }                                                                     \
    } while (0)
#define RD_B(dst, BUF, NI)                                                    \
    do {                                                                      \
        dst[0] = *(const short8*)&sBf[(BUF) * 8192 + bRd0 + (NI) * 16 * 64];  \
        dst[1] = *(const short8*)&sBf[(BUF) * 8192 + bRd1 + (NI) * 16 * 64];  \
    } while (0)
#define MFMA8(BF, NI)                                                         \
    do {                                                                      \
        _Pragma("unroll")                                                     \
        for (int kh = 0; kh < 2; ++kh)                                        \
            _Pragma("unroll")                                                 \
            for (int mi = 0; mi < 4; ++mi)                                    \
                acc[mi][NI] = __builtin_amdgcn_mfma_f32_16x16x32_bf16(        \
                    afc[mi][kh], BF[kh], acc[mi][NI], 0, 0, 0);               \
    } while (0)

    floatx4 acc[4][2];
#pragma unroll
    for (int i = 0; i < 4; ++i)
#pragma unroll
        for (int j = 0; j < 2; ++j) acc[i][j] = (floatx4){0.f, 0.f, 0.f, 0.f};

    short8 afc[4][2], bf0[2], bf1[2];

    STAGE_A(0, aStage - 64);
    STAGE_B(0, bStage - 128);
    STAGE_B(1, bStage - 64);
    VMC2();
    BAR();
    RD_A(afc, 0);
    RD_B(bf0, 0, 0);
    SB0();

#define TILE(CUR, NXT)                                                        \
    LGKM0();                                                                  \
    PRIO1();                                                                  \
    MFMA8(bf0, 0);                                                            \
    PRIO0();                                                                  \
    SB0();                                                                    \
    RD_B(bf1, CUR, 1);                                                        \
    STAGE_A(NXT, aStage);                                                     \
    BAR();                                                                    \
    LGKM0();                                                                  \
    PRIO1();                                                                  \
    MFMA8(bf1, 1);                                                            \
    PRIO0();                                                                  \
    SB0();                                                                    \
    STAGE_B(CUR, bStage);                                                     \
    VMC2(); /* A(t+1), B(t+1) landed; B(t+2) in flight */                     \
    BAR();                                                                    \
    RD_A(afc, NXT);                                                           \
    RD_B(bf0, NXT, 0);                                                        \
    SB0();                                                                    \
    aStage += 64;                                                             \
    bStage += 64;

    const int NT = K >> 6;  // 32 here (even)
    for (int t = 0; t < NT; t += 2) {
        TILE(0, 1)
        TILE(1, 0)
    }
#undef TILE

    asm volatile("s_waitcnt vmcnt(0)" ::: "memory");  // drain overrun stages

    const int cc = lane & 15;
    const int rb = (lane >> 4) * 4;
#pragma unroll
    for (int mi = 0; mi < 4; ++mi)
#pragma unroll
        for (int ni = 0; ni < 2; ++ni)
#pragma unroll
            for (int r = 0; r < 4; ++r) {
                int grow = bm + wm * 64 + mi * 16 + rb + r;
                int gcol = bn + wn * 32 + ni * 16 + cc;
                float v = acc[mi][ni][r];
                if (OUT_BF16)
                    ((u16*)Cout)[(size_t)grow * N + gcol] = f2bf(v);
                else
                    ((float*)Cout)[(size_t)grow * N + gcol] = v;
            }
#undef STAGE_A
#undef STAGE_B
#undef RD_A
#undef RD_B
#undef MFMA8
}

// depthwise causal conv (DC=4) + bias + silu + row-mean.
__global__ __launch_bounds__(256) void conv_silu_avg(
    const u16* __restrict__ xin, const float* __restrict__ cw,
    const float* __restrict__ cb, u16* __restrict__ xconv,
    float* __restrict__ xavg) {
    const int blk = blockIdx.x;        // 512 blocks
    const int b = blk >> 7;
    const int lc = blk & 127;
    const int row0 = b * LL + lc * 16;
    const int tid = threadIdx.x;
    const int lane = tid & 63, wave = tid >> 6;
    const int d0 = tid * 8;
    float4 cwv[8];
    float cbv[8];
#pragma unroll
    for (int e = 0; e < 8; ++e) cwv[e] = *(const float4*)&cw[(d0 + e) * 4];
#pragma unroll
    for (int e = 0; e < 8; e += 4) {
        float4 c = *(const float4*)&cb[d0 + e];
        cbv[e] = c.x; cbv[e + 1] = c.y; cbv[e + 2] = c.z; cbv[e + 3] = c.w;
    }
    u16x8 w0, w1, w2;
    if (lc == 0) {
        w0 = (u16x8)0; w1 = (u16x8)0; w2 = (u16x8)0;
    } else {
        w0 = *(const u16x8*)&xin[(size_t)(row0 - 3) * (2 * DINNER) + d0];
        w1 = *(const u16x8*)&xin[(size_t)(row0 - 2) * (2 * DINNER) + d0];
        w2 = *(const u16x8*)&xin[(size_t)(row0 - 1) * (2 * DINNER) + d0];
    }
    float sums[16];
#pragma unroll
    for (int t = 0; t < 16; ++t) {
        u16x8 cur = *(const u16x8*)&xin[(size_t)(row0 + t) * (2 * DINNER) + d0];
        float lsum = 0.f;
        u16x8 o;
#pragma unroll
        for (int e = 0; e < 8; ++e) {
            float acc = cbv[e];
            acc += bf2f(w0[e]) * cwv[e].x;
            acc += bf2f(w1[e]) * cwv[e].y;
            acc += bf2f(w2[e]) * cwv[e].z;
            acc += bf2f(cur[e]) * cwv[e].w;
            float s = silu_f(acc);
            lsum += s;
            o[e] = f2bf(s);
        }
        *(u16x8*)&xconv[(size_t)(row0 + t) * DINNER + d0] = o;
        sums[t] = lsum;
        w0 = w1; w1 = w2; w2 = cur;
    }
#pragma unroll
    for (int off = 32; off; off >>= 1)
#pragma unroll
        for (int t = 0; t < 16; ++t) sums[t] += __shfl_down(sums[t], off);
    __shared__ float wred[4][16];
    if (lane == 0) {
#pragma unroll
        for (int t = 0; t < 16; ++t) wred[wave][t] = sums[t];
    }
    __syncthreads();
    if (tid < 16)
        xavg[row0 + tid] = (wred[0][tid] + wred[1][tid] + wred[2][tid] + wred[3][tid]) *
                           (1.f / DINNER);
}

// delta/B/C projections: thin GEMM (8192 x 48 x 2048), K split across waves.
__global__ __launch_bounds__(256) void dbc_direct(
    const u16* __restrict__ xconv, const u16* __restrict__ wcat,
    const float* __restrict__ db, const float* __restrict__ A_log,
    const float* __restrict__ xavg,
    float* __restrict__ a_out, float* __restrict__ u_out, float* __restrict__ c_out) {
    __shared__ float part[4][32][48];
    const int tid = threadIdx.x;
    const int lane = tid & 63;
    const int wave = tid >> 6;
    const int bm = blockIdx.x * 32;
    const int fr = lane & 15;
    const int kq = lane >> 4;
    const int k0 = wave * 512 + kq * 8;

    const u16* ap0 = xconv + (size_t)(bm + fr) * DINNER + k0;
    const u16* ap1 = xconv + (size_t)(bm + 16 + fr) * DINNER + k0;
    const u16* bp0 = wcat + (size_t)(fr) * DINNER + k0;
    const u16* bp1 = wcat + (size_t)(16 + fr) * DINNER + k0;
    const u16* bp2 = wcat + (size_t)(32 + fr) * DINNER + k0;

    floatx4 acc[2][3];
#pragma unroll
    for (int mi = 0; mi < 2; ++mi)
#pragma unroll
        for (int ni = 0; ni < 3; ++ni) acc[mi][ni] = (floatx4){0.f, 0.f, 0.f, 0.f};

#pragma unroll 4
    for (int kk = 0; kk < 16; ++kk) {
        short8 a0 = *(const short8*)ap0;
        short8 a1 = *(const short8*)ap1;
        short8 b0 = *(const short8*)bp0;
        short8 b1 = *(const short8*)bp1;
        short8 b2 = *(const short8*)bp2;
        ap0 += 32; ap1 += 32; bp0 += 32; bp1 += 32; bp2 += 32;
        acc[0][0] = __builtin_amdgcn_mfma_f32_16x16x32_bf16(a0, b0, acc[0][0], 0, 0, 0);
        acc[0][1] = __builtin_amdgcn_mfma_f32_16x16x32_bf16(a0, b1, acc[0][1], 0, 0, 0);
        acc[0][2] = __builtin_amdgcn_mfma_f32_16x16x32_bf16(a0, b2, acc[0][2], 0, 0, 0);
        acc[1][0] = __builtin_amdgcn_mfma_f32_16x16x32_bf16(a1, b0, acc[1][0], 0, 0, 0);
        acc[1][1] = __builtin_amdgcn_mfma_f32_16x16x32_bf16(a1, b1, acc[1][1], 0, 0, 0);
        acc[1][2] = __builtin_amdgcn_mfma_f32_16x16x32_bf16(a1, b2, acc[1][2], 0, 0, 0);
    }
    // C/D 16x16 layout: col = lane&15, row = (lane>>4)*4 + r
    const int cr = kq * 4;
#pragma unroll
    for (int mi = 0; mi < 2; ++mi)
#pragma unroll
        for (int ni = 0; ni < 3; ++ni)
#pragma unroll
            for (int r = 0; r < 4; ++r)
                part[wave][mi * 16 + cr + r][ni * 16 + fr] = acc[mi][ni][r];
    __syncthreads();
#pragma unroll
    for (int it = tid; it < 512; it += 256) {
        int row = it >> 4;
        int s = it & 15;
        float sd = 0.f, sb = 0.f, sc = 0.f;
#pragma unroll
        for (int w = 0; w < 4; ++w) {
            sd += part[w][row][s];
            sb += part[w][row][s + 16];
            sc += part[w][row][s + 32];
        }
        int grow = bm + row;
        float Aa = -__expf(A_log[s]);
        float pre = sd + db[s];
        float delta = (pre > 20.f) ? pre : log1pf(__expf(pre));
        a_out[grow * NSTATE + s] = __expf(delta * Aa);
        u_out[grow * NSTATE + s] = delta * sb * xavg[grow];
        c_out[grow * NSTATE + s] = sc;
    }
}

// ---- fused parallel linear scan: one kernel, 4 blocks (one per batch) ----
__global__ __launch_bounds__(1024) void scan_fused(
    const float* __restrict__ a, const float* __restrict__ u,
    const float* __restrict__ c, float* __restrict__ y) {
    const int b = blockIdx.x;
    const int tid = threadIdx.x;
    const int s = tid & 15;
    const int seg = tid >> 4;   // 0..63
    __shared__ float Ps[NSEG][NSTATE];
    __shared__ float Hs[NSEG][NSTATE];
    __shared__ float HSs[NSEG][NSTATE];

    size_t base = (size_t)(b * LL + seg * SEGLEN) * NSTATE + s;
    float P = 1.f, h = 0.f;
#pragma unroll 8
    for (int t = 0; t < SEGLEN; ++t) {
        float av = a[base + (size_t)t * NSTATE];
        float uv = u[base + (size_t)t * NSTATE];
        h = fmaf(av, h, uv);
        P *= av;
    }
    Ps[seg][s] = P;
    Hs[seg][s] = h;
    __syncthreads();
    if (tid < 16) {
        float hh = 0.f;
        for (int g = 0; g < NSEG; ++g) {
            HSs[g][tid] = hh;
            hh = fmaf(Ps[g][tid], hh, Hs[g][tid]);
        }
    }
    __syncthreads();
    float h2 = HSs[seg][s];
#pragma unroll 8
    for (int t = 0; t < SEGLEN; ++t) {
        float av = a[base + (size_t)t * NSTATE];
        float uv = u[base + (size_t)t * NSTATE];
        float cv = c[base + (size_t)t * NSTATE];
        h2 = fmaf(av, h2, uv);
        float p = h2 * cv;
        p += __shfl_xor(p, 1);
        p += __shfl_xor(p, 2);
        p += __shfl_xor(p, 4);
        p += __shfl_xor(p, 8);
        if (s == 0) y[b * LL + seg * SEGLEN + t] = p;
    }
}

// y_skip = y*silu(x_gate) + x_conv*D  -> bf16
__global__ __launch_bounds__(256) void gate_skip(
    const u16* __restrict__ xin, const float* __restrict__ y,
    const float* __restrict__ Dv, const u16* __restrict__ xconv,
    u16* __restrict__ yskip) {
    size_t i = ((size_t)blockIdx.x * 256 + threadIdx.x) * 8;
    int row = (int)(i >> 11);
    int d = (int)(i & (DINNER - 1));
    u16x8 g = *(const u16x8*)&xin[(size_t)row * (2 * DINNER) + DINNER + d];
    u16x8 xc = *(const u16x8*)&xconv[i];
    float yv = y[row];
    u16x8 o;
#pragma unroll
    for (int e = 0; e < 8; ++e) {
        float gv = silu_f(bf2f(g[e]));
        float v = yv * gv + bf2f(xc[e]) * Dv[d + e];
        o[e] = f2bf(v);
    }
    *(u16x8*)&yskip[i] = o;
}

extern "C" void kernel_launch(void* const* d_in, const int* in_sizes, int n_in,
                              void* d_out, int out_size, void* d_ws, size_t ws_size,
                              hipStream_t stream) {
    const float* x       = (const float*)d_in[0];
    const float* w_in    = (const float*)d_in[1];
    const float* conv_w  = (const float*)d_in[2];
    const float* conv_b  = (const float*)d_in[3];
    const float* A_log   = (const float*)d_in[4];
    const float* Dv      = (const float*)d_in[5];
    const float* delta_w = (const float*)d_in[6];
    const float* delta_b = (const float*)d_in[7];
    const float* B_w     = (const float*)d_in[8];
    const float* C_w     = (const float*)d_in[9];
    const float* out_w   = (const float*)d_in[10];
    float* out = (float*)d_out;

    u16* xb  = (u16*)d_ws;                 // 8192*1024
    u16* wb  = xb + 8388608;               // 4096*1024
    u16* owb = wb + 4194304;               // 1024*2048
    u16* wsb = owb + 2097152;              // 48*2048 (concat dw,bw,cw)
    u16* xin = wsb + 98304;                // 8192*4096
    u16* xcv = xin + 33554432;             // 8192*2048
    u16* ysk = xcv + 16777216;             // 8192*2048
    float* fb     = (float*)(ysk + 16777216);
    float* abuf   = fb;                    // 8192*16
    float* ubuf   = abuf + 131072;
    float* cbuf   = ubuf + 131072;
    float* ybuf   = cbuf + 131072;         // 8192
    float* avgbuf = ybuf + 8192;           // 8192

    cvt_multi<<<7216, 256, 0, stream>>>(x, w_in, out_w, delta_w, B_w, C_w,
                                        xb, wb, owb, wsb, wsb + 32768, wsb + 65536);

    // x_inner = x @ in_proj_w.T : (8192x1024)@(4096x1024)^T -> bf16
    gemm_bt_256<1><<<dim3(16, 32), 512, 0, stream>>>(xb, wb, xin, 2 * DINNER, DMODEL);

    conv_silu_avg<<<512, 256, 0, stream>>>(xin, conv_w, conv_b, xcv, avgbuf);
    dbc_direct<<<256, 256, 0, stream>>>(xcv, wsb, delta_b, A_log, avgbuf,
                                        abuf, ubuf, cbuf);

    scan_fused<<<4, 1024, 0, stream>>>(abuf, ubuf, cbuf, ybuf);

    gate_skip<<<NROW * DINNER / 8 / 256, 256, 0, stream>>>(xin, ybuf, Dv, xcv, ysk);

    // out = y_skip @ out_proj_w.T : (8192x2048)@(1024x2048)^T -> fp32
    gemm_bt_128p<0><<<dim3(8, 64), 512, 0, stream>>>(ysk, owb, out, DMODEL, DINNER);
}

// Round 8
// 313.403 us; speedup vs baseline: 1.0222x; 1.0222x over previous
//
#include <hip/hip_runtime.h>
#include <cmath>

#define LL 2048
#define NROW 8192
#define DMODEL 1024
#define DINNER 2048
#define NSTATE 16
#define NSEG 64
#define SEGLEN 32   // NSEG * SEGLEN == LL

typedef unsigned short u16;
typedef __attribute__((ext_vector_type(8))) unsigned short u16x8;
typedef __attribute__((ext_vector_type(8))) short short8;
typedef __attribute__((ext_vector_type(4))) float floatx4;
typedef __attribute__((ext_vector_type(16))) float floatx16;

__device__ __forceinline__ float bf2f(u16 h) {
    unsigned u = ((unsigned)h) << 16;
    float f;
    __builtin_memcpy(&f, &u, 4);
    return f;
}
__device__ __forceinline__ u16 f2bf(float f) {
    unsigned u;
    __builtin_memcpy(&u, &f, 4);
    u = u + 0x7fffu + ((u >> 16) & 1u);
    return (u16)(u >> 16);
}
__device__ __forceinline__ float silu_f(float x) { return x / (1.f + __expf(-x)); }

// One kernel converts all six fp32->bf16 tensors (2048 elems per block).
__global__ __launch_bounds__(256) void cvt_multi(
    const float* __restrict__ s0, const float* __restrict__ s1,
    const float* __restrict__ s2, const float* __restrict__ s3,
    const float* __restrict__ s4, const float* __restrict__ s5,
    u16* __restrict__ d0, u16* __restrict__ d1, u16* __restrict__ d2,
    u16* __restrict__ d3, u16* __restrict__ d4, u16* __restrict__ d5) {
    int bid = blockIdx.x;
    const float* s;
    u16* d;
    size_t off;
    if (bid < 4096)      { s = s0; d = d0; off = (size_t)bid * 2048; }
    else if (bid < 6144) { s = s1; d = d1; off = (size_t)(bid - 4096) * 2048; }
    else if (bid < 7168) { s = s2; d = d2; off = (size_t)(bid - 6144) * 2048; }
    else if (bid < 7184) { s = s3; d = d3; off = (size_t)(bid - 7168) * 2048; }
    else if (bid < 7200) { s = s4; d = d4; off = (size_t)(bid - 7184) * 2048; }
    else                 { s = s5; d = d5; off = (size_t)(bid - 7200) * 2048; }
    size_t i = off + (size_t)threadIdx.x * 8;
    float4 a = *(const float4*)&s[i];
    float4 b = *(const float4*)&s[i + 4];
    u16x8 o;
    o[0] = f2bf(a.x); o[1] = f2bf(a.y); o[2] = f2bf(a.z); o[3] = f2bf(a.w);
    o[4] = f2bf(b.x); o[5] = f2bf(b.y); o[6] = f2bf(b.z); o[7] = f2bf(b.w);
    *(u16x8*)&d[i] = o;
}

#define GL_LDS(gp, lp)                                                        \
    __builtin_amdgcn_global_load_lds(                                         \
        (const __attribute__((address_space(1))) void*)(gp),                  \
        (__attribute__((address_space(3))) void*)(lp), 16, 0, 0)
#define BAR() __builtin_amdgcn_s_barrier()
#define SB0() __builtin_amdgcn_sched_barrier(0)
#define LGKM0()                                                               \
    do {                                                                      \
        asm volatile("s_waitcnt lgkmcnt(0)" ::: "memory");                    \
        __builtin_amdgcn_sched_barrier(0);                                    \
    } while (0)
#define VMC4() asm volatile("s_waitcnt vmcnt(4)" ::: "memory")
#define VMC2() asm volatile("s_waitcnt vmcnt(2)" ::: "memory")
#define PRIO1() __builtin_amdgcn_s_setprio(1)
#define PRIO0() __builtin_amdgcn_s_setprio(0)

// ---------------------------------------------------------------------------
// 256x256 GEMM (C = A @ B^T), reads-after-MFMA pipelined 4-phase schedule.
// R6-verified base (73.2 us, MfmaUtil 37%, 0 conflicts, no spill), with ONE
// minimal change (R8): the two reads whose destination registers are dead at
// phase start (bf23 in ph1, afY in ph2) are issued BEFORE that phase's MFMA
// cluster, so they land under the ~600-cyc MFMA and the following phase's
// lgkmcnt(0) is free. The ph3 (bf01') and ph4 (afX') reads stay post-MFMA
// (they overwrite that MFMA's operands). Live-set is unchanged vs R4/R6.
// 2 barriers/tile (mid + end), each preceded by counted vmcnt(4):
//   mid  (after ph2): B(t+1) landed ; end (after ph4): A(t+1) landed.
// Staging train: A(t+1) at ph1/ph2, B(t+2) at ph3/ph4. Never vmcnt(0).
// Staging pointers overrun K-end by <=2 tiles into the adjacent workspace
// allocation (callers: xb->wb, wb->owb readable).
// LDS swizzle: [128][64]-elem half-tiles, stored slot = g ^ (row&7).
// XCD-aware bijective block swizzle (grid % 8 == 0).
// ---------------------------------------------------------------------------
template <int OUT_BF16>
__global__ __launch_bounds__(512, 2) void gemm_bt_256(
    const u16* __restrict__ A, const u16* __restrict__ B,
    void* __restrict__ Cout, int N, int K) {
    __shared__ u16 sAf[2 * 2 * 128 * 64];   // [buf][half][row*64 + slot*8]
    __shared__ u16 sBf[2 * 2 * 128 * 64];
    const int tid = threadIdx.x;
    const int lane = tid & 63;
    const int wave = tid >> 6;   // 0..7
    const int wm = wave >> 2;    // 0..1
    const int wn = wave & 3;     // 0..3

    // XCD swizzle: linearize grid, chunk per XCD (nwg % 8 == 0 here).
    const int gx = gridDim.x;
    const int nwg = gx * gridDim.y;
    const int cpx = nwg >> 3;
    int lin = blockIdx.y * gx + blockIdx.x;
    int swz = (lin & 7) * cpx + (lin >> 3);
    const int bm = (swz / gx) * 256;
    const int bn = (swz % gx) * 256;

    // ---- staging addresses (pre-swizzled source k-slot) ----
    const int gslot = (lane & 7) ^ ((lane >> 3) & 7);
    const int srowoff = lane >> 3;                  // 0..7
    const u16* aStage = A + (size_t)(bm + wave * 8 + srowoff) * K + gslot * 8 + 64;
    const u16* bStage = B + (size_t)(bn + wave * 8 + srowoff) * K + gslot * 8 + 128;
    const size_t row64 = (size_t)64 * K;
    const size_t row128 = (size_t)128 * K;

#define STAGE_A(BUF, H, PTR)                                                  \
    do {                                                                      \
        GL_LDS((PTR) + (H) * row128,         &sAf[(BUF) * 16384 + (H) * 8192 + wave * 512]); \
        GL_LDS((PTR) + (H) * row128 + row64, &sAf[(BUF) * 16384 + (H) * 8192 + (8 + wave) * 512]); \
    } while (0)
#define STAGE_B(BUF, H, PTR)                                                  \
    do {                                                                      \
        GL_LDS((PTR) + (H) * row128,         &sBf[(BUF) * 16384 + (H) * 8192 + wave * 512]); \
        GL_LDS((PTR) + (H) * row128 + row64, &sBf[(BUF) * 16384 + (H) * 8192 + (8 + wave) * 512]); \
    } while (0)

    // ---- fragment read bases (element offsets) ----
    const int fr = lane & 15;
    const int kq = lane >> 4;
    const int st0 = kq ^ (fr & 7);
    const int st1 = (4 + kq) ^ (fr & 7);
    const int aRd0 = wm * 8192 + fr * 64 + st0 * 8;
    const int aRd1 = wm * 8192 + fr * 64 + st1 * 8;
    const int bRow = (wn & 1) * 64 + fr;
    const int bRd0 = (wn >> 1) * 8192 + bRow * 64 + st0 * 8;
    const int bRd1 = (wn >> 1) * 8192 + bRow * 64 + st1 * 8;

#define RD_A(dst, BUF, R0)                                                    \
    do {                                                                      \
        _Pragma("unroll")                                                     \
        for (int mi = 0; mi < 4; ++mi) {                                      \
            dst[mi][0] = *(const short8*)&sAf[(BUF) * 16384 + aRd0 + ((R0) + mi * 16) * 64]; \
            dst[mi][1] = *(const short8*)&sAf[(BUF) * 16384 + aRd1 + ((R0) + mi * 16) * 64]; \
        }                                                                     \
    } while (0)
#define RD_B(dst, BUF, R0)                                                    \
    do {                                                                      \
        _Pragma("unroll")                                                     \
        for (int ni = 0; ni < 2; ++ni) {                                      \
            dst[ni][0] = *(const short8*)&sBf[(BUF) * 16384 + bRd0 + ((R0) + ni * 16) * 64]; \
            dst[ni][1] = *(const short8*)&sBf[(BUF) * 16384 + bRd1 + ((R0) + ni * 16) * 64]; \
        }                                                                     \
    } while (0)
#define MFMA_PH(AF, RB, BF, CB)                                               \
    do {                                                                      \
        _Pragma("unroll")                                                     \
        for (int kh = 0; kh < 2; ++kh)                                        \
            _Pragma("unroll")                                                 \
            for (int mi = 0; mi < 4; ++mi)                                    \
                _Pragma("unroll")                                             \
                for (int ni = 0; ni < 2; ++ni)                                \
                    acc[(RB) + mi][(CB) + ni] =                               \
                        __builtin_amdgcn_mfma_f32_16x16x32_bf16(              \
                            AF[mi][kh], BF[ni][kh],                           \
                            acc[(RB) + mi][(CB) + ni], 0, 0, 0);              \
    } while (0)

    floatx4 acc[8][4];
#pragma unroll
    for (int i = 0; i < 8; ++i)
#pragma unroll
        for (int j = 0; j < 4; ++j) acc[i][j] = (floatx4){0.f, 0.f, 0.f, 0.f};

    short8 afX[4][2], afY[4][2], bf01[2][2], bf23[2][2];

    // ---- prologue: stage A(0),B(0),B(1); vmcnt(4) leaves B(1) in flight ----
    {
        const u16* a0 = aStage - 64;
        const u16* b0 = bStage - 128;
        STAGE_A(0, 0, a0);
        STAGE_A(0, 1, a0);
        STAGE_B(0, 0, b0);
        STAGE_B(0, 1, b0);
        STAGE_B(1, 0, b0 + 64);
        STAGE_B(1, 1, b0 + 64);
    }
    VMC4();
    BAR();
    RD_A(afX, 0, 0);
    RD_B(bf01, 0, 0);
    SB0();

// TILE body; CUR/NXT compile-time via x2 unroll.
// R8 change vs R6: bf23 read hoisted before ph1's MFMA, afY before ph2's
// (dest regs dead at those points; lands under MFMA so the next phase's
// lgkm0 is free). bf01'/afX' reads remain post-MFMA (operand overwrite).
#define TILE(CUR, NXT)                                                        \
    /* ph1: drain afX'(prev); read bf23(cur) [dead regs]; MFMA; stage A0 */   \
    LGKM0();                                                                  \
    RD_B(bf23, CUR, 32);                                                      \
    SB0();                                                                    \
    PRIO1();                                                                  \
    MFMA_PH(afX, 0, bf01, 0);                                                 \
    PRIO0();                                                                  \
    SB0();                                                                    \
    STAGE_A(NXT, 0, aStage);                                                  \
    SB0();                                                                    \
    /* ph2: lgkm free (bf23 landed); read afY(cur) [dead]; MFMA; mid sync */  \
    LGKM0();                                                                  \
    RD_A(afY, CUR, 64);                                                       \
    SB0();                                                                    \
    PRIO1();                                                                  \
    MFMA_PH(afX, 0, bf23, 2);                                                 \
    PRIO0();                                                                  \
    SB0();                                                                    \
    STAGE_A(NXT, 1, aStage);                                                  \
    VMC4(); /* B(t+1) landed */                                               \
    BAR();                                                                    \
    /* ph3: lgkm free (afY landed); MFMA; read bf01'(nxt); stage B0(t+2) */   \
    LGKM0();                                                                  \
    PRIO1();                                                                  \
    MFMA_PH(afY, 4, bf01, 0);                                                 \
    PRIO0();                                                                  \
    SB0();                                                                    \
    RD_B(bf01, NXT, 0);                                                       \
    STAGE_B(CUR, 0, bStage);                                                  \
    SB0();                                                                    \
    /* ph4: MFMA (operands in regs); stage B1(t+2); end sync; read afX' */    \
    PRIO1();                                                                  \
    MFMA_PH(afY, 4, bf23, 2);                                                 \
    PRIO0();                                                                  \
    SB0();                                                                    \
    STAGE_B(CUR, 1, bStage);                                                  \
    VMC4(); /* A(t+1) landed */                                               \
    BAR();                                                                    \
    RD_A(afX, NXT, 0);                                                        \
    SB0();                                                                    \
    aStage += 64;                                                             \
    bStage += 64;

    const int NT = K >> 6;  // even (16 here)
    for (int t = 0; t < NT; t += 2) {
        TILE(0, 1)
        TILE(1, 0)
    }
#undef TILE

    // epilogue: C/D 16x16 layout: col = lane&15, row = (lane>>4)*4 + r
    const int cc = lane & 15;
    const int rb = (lane >> 4) * 4;
#pragma unroll
    for (int mi = 0; mi < 8; ++mi)
#pragma unroll
        for (int ni = 0; ni < 4; ++ni)
#pragma unroll
            for (int r = 0; r < 4; ++r) {
                int grow = bm + wm * 128 + mi * 16 + rb + r;
                int gcol = bn + wn * 64 + ni * 16 + cc;
                float v = acc[mi][ni][r];
                if (OUT_BF16)
                    ((u16*)Cout)[(size_t)grow * N + gcol] = f2bf(v);
                else
                    ((float*)Cout)[(size_t)grow * N + gcol] = v;
            }
#undef STAGE_A
#undef STAGE_B
#undef RD_A
#undef RD_B
#undef MFMA_PH
}

// ---------------------------------------------------------------------------
// 128x128 GEMM (C = A @ B^T), pipelined schedule at 128-tile for the thin
// out-proj (N=1024 -> 512 blocks). BK=64, 8 waves (2M x 4N), per-wave C =
// 64x32. LDS 64 KiB dbuf -> 2 blocks/CU (4 waves/SIMD). 2 phases/tile,
// 2 barriers, counted vmcnt(2). (R6-verified; R8: bf1 read hoisted before
// ph1's MFMA -- dest regs dead, ph2's lgkm0 becomes free.)
// ---------------------------------------------------------------------------
template <int OUT_BF16>
__global__ __launch_bounds__(512, 4) void gemm_bt_128p(
    const u16* __restrict__ A, const u16* __restrict__ B,
    void* __restrict__ Cout, int N, int K) {
    __shared__ u16 sAf[2 * 128 * 64];   // [buf][row*64 + slot*8]
    __shared__ u16 sBf[2 * 128 * 64];
    const int tid = threadIdx.x;
    const int lane = tid & 63;
    const int wave = tid >> 6;   // 0..7
    const int wm = wave >> 2;    // 0..1  (M half: 64 rows)
    const int wn = wave & 3;     // 0..3  (N quarter: 32 cols)

    const int gx = gridDim.x;
    const int nwg = gx * gridDim.y;
    const int cpx = nwg >> 3;                       // nwg % 8 == 0 here
    int lin = blockIdx.y * gx + blockIdx.x;
    int swz = (lin & 7) * cpx + (lin >> 3);
    const int bm = (swz / gx) * 128;
    const int bn = (swz % gx) * 128;

    const int gslot = (lane & 7) ^ ((lane >> 3) & 7);
    const int srowoff = lane >> 3;                  // 0..7
    const u16* aStage = A + (size_t)(bm + wave * 8 + srowoff) * K + gslot * 8 + 64;
    const u16* bStage = B + (size_t)(bn + wave * 8 + srowoff) * K + gslot * 8 + 128;
    const size_t row64 = (size_t)64 * K;

#define STAGE_A(BUF, PTR)                                                     \
    do {                                                                      \
        GL_LDS((PTR),         &sAf[(BUF) * 8192 + wave * 512]);               \
        GL_LDS((PTR) + row64, &sAf[(BUF) * 8192 + (8 + wave) * 512]);         \
    } while (0)
#define STAGE_B(BUF, PTR)                                                     \
    do {                                                                      \
        GL_LDS((PTR),         &sBf[(BUF) * 8192 + wave * 512]);               \
        GL_LDS((PTR) + row64, &sBf[(BUF) * 8192 + (8 + wave) * 512]);         \
    } while (0)

    const int fr = lane & 15;
    const int kq = lane >> 4;
    const int st0 = kq ^ (fr & 7);
    const int st1 = (4 + kq) ^ (fr & 7);
    const int aRd0 = (wm * 64 + fr) * 64 + st0 * 8;
    const int aRd1 = (wm * 64 + fr) * 64 + st1 * 8;
    const int bRd0 = (wn * 32 + fr) * 64 + st0 * 8;
    const int bRd1 = (wn * 32 + fr) * 64 + st1 * 8;

#define RD_A(dst, BUF)                                                        \
    do {                                                                      \
        _Pragma("unroll")                                                     \
        for (int mi = 0; mi < 4; ++mi) {                                      \
            dst[mi][0] = *(const short8*)&sAf[(BUF) * 8192 + aRd0 + mi * 16 * 64]; \
            dst[mi][1] = *(const short8*)&sAf[(BUF) * 8192 + aRd1 + mi * 16 * 64]; \
        }                                                                     \
    } while (0)
#define RD_B(dst, BUF, NI)                                                    \
    do {                                                                      \
        dst[0] = *(const short8*)&sBf[(BUF) * 8192 + bRd0 + (NI) * 16 * 64];  \
        dst[1] = *(const short8*)&sBf[(BUF) * 8192 + bRd1 + (NI) * 16 * 64];  \
    } while (0)
#define MFMA8(BF, NI)                                                         \
    do {                                                                      \
        _Pragma("unroll")                                                     \
        for (int kh = 0; kh < 2; ++kh)                                        \
            _Pragma("unroll")                                                 \
            for (int mi = 0; mi < 4; ++mi)                                    \
                acc[mi][NI] = __builtin_amdgcn_mfma_f32_16x16x32_bf16(        \
                    afc[mi][kh], BF[kh], acc[mi][NI], 0, 0, 0);               \
    } while (0)

    floatx4 acc[4][2];
#pragma unroll
    for (int i = 0; i < 4; ++i)
#pragma unroll
        for (int j = 0; j < 2; ++j) acc[i][j] = (floatx4){0.f, 0.f, 0.f, 0.f};

    short8 afc[4][2], bf0[2], bf1[2];

    STAGE_A(0, aStage - 64);
    STAGE_B(0, bStage - 128);
    STAGE_B(1, bStage - 64);
    VMC2();
    BAR();
    RD_A(afc, 0);
    RD_B(bf0, 0, 0);
    SB0();

#define TILE(CUR, NXT)                                                        \
    /* ph1: drain tile-end reads; read bf1(cur) [dead regs]; MFMA; stage A */ \
    LGKM0();                                                                  \
    RD_B(bf1, CUR, 1);                                                        \
    SB0();                                                                    \
    PRIO1();                                                                  \
    MFMA8(bf0, 0);                                                            \
    PRIO0();                                                                  \
    SB0();                                                                    \
    STAGE_A(NXT, aStage);                                                     \
    BAR();                                                                    \
    /* ph2: lgkm free (bf1 landed); MFMA; stage B(t+2); end sync; reads */    \
    LGKM0();                                                                  \
    PRIO1();                                                                  \
    MFMA8(bf1, 1);                                                            \
    PRIO0();                                                                  \
    SB0();                                                                    \
    STAGE_B(CUR, bStage);                                                     \
    VMC2(); /* A(t+1), B(t+1) landed; B(t+2) in flight */                     \
    BAR();                                                                    \
    RD_A(afc, NXT);                                                           \
    RD_B(bf0, NXT, 0);                                                        \
    SB0();                                                                    \
    aStage += 64;                                                             \
    bStage += 64;

    const int NT = K >> 6;  // 32 here (even)
    for (int t = 0; t < NT; t += 2) {
        TILE(0, 1)
        TILE(1, 0)
    }
#undef TILE

    asm volatile("s_waitcnt vmcnt(0)" ::: "memory");  // drain overrun stages

    const int cc = lane & 15;
    const int rb = (lane >> 4) * 4;
#pragma unroll
    for (int mi = 0; mi < 4; ++mi)
#pragma unroll
        for (int ni = 0; ni < 2; ++ni)
#pragma unroll
            for (int r = 0; r < 4; ++r) {
                int grow = bm + wm * 64 + mi * 16 + rb + r;
                int gcol = bn + wn * 32 + ni * 16 + cc;
                float v = acc[mi][ni][r];
                if (OUT_BF16)
                    ((u16*)Cout)[(size_t)grow * N + gcol] = f2bf(v);
                else
                    ((float*)Cout)[(size_t)grow * N + gcol] = v;
            }
#undef STAGE_A
#undef STAGE_B
#undef RD_A
#undef RD_B
#undef MFMA8
}

// depthwise causal conv (DC=4) + bias + silu + row-mean.
__global__ __launch_bounds__(256) void conv_silu_avg(
    const u16* __restrict__ xin, const float* __restrict__ cw,
    const float* __restrict__ cb, u16* __restrict__ xconv,
    float* __restrict__ xavg) {
    const int blk = blockIdx.x;        // 512 blocks
    const int b = blk >> 7;
    const int lc = blk & 127;
    const int row0 = b * LL + lc * 16;
    const int tid = threadIdx.x;
    const int lane = tid & 63, wave = tid >> 6;
    const int d0 = tid * 8;
    float4 cwv[8];
    float cbv[8];
#pragma unroll
    for (int e = 0; e < 8; ++e) cwv[e] = *(const float4*)&cw[(d0 + e) * 4];
#pragma unroll
    for (int e = 0; e < 8; e += 4) {
        float4 c = *(const float4*)&cb[d0 + e];
        cbv[e] = c.x; cbv[e + 1] = c.y; cbv[e + 2] = c.z; cbv[e + 3] = c.w;
    }
    u16x8 w0, w1, w2;
    if (lc == 0) {
        w0 = (u16x8)0; w1 = (u16x8)0; w2 = (u16x8)0;
    } else {
        w0 = *(const u16x8*)&xin[(size_t)(row0 - 3) * (2 * DINNER) + d0];
        w1 = *(const u16x8*)&xin[(size_t)(row0 - 2) * (2 * DINNER) + d0];
        w2 = *(const u16x8*)&xin[(size_t)(row0 - 1) * (2 * DINNER) + d0];
    }
    float sums[16];
#pragma unroll
    for (int t = 0; t < 16; ++t) {
        u16x8 cur = *(const u16x8*)&xin[(size_t)(row0 + t) * (2 * DINNER) + d0];
        float lsum = 0.f;
        u16x8 o;
#pragma unroll
        for (int e = 0; e < 8; ++e) {
            float acc = cbv[e];
            acc += bf2f(w0[e]) * cwv[e].x;
            acc += bf2f(w1[e]) * cwv[e].y;
            acc += bf2f(w2[e]) * cwv[e].z;
            acc += bf2f(cur[e]) * cwv[e].w;
            float s = silu_f(acc);
            lsum += s;
            o[e] = f2bf(s);
        }
        *(u16x8*)&xconv[(size_t)(row0 + t) * DINNER + d0] = o;
        sums[t] = lsum;
        w0 = w1; w1 = w2; w2 = cur;
    }
#pragma unroll
    for (int off = 32; off; off >>= 1)
#pragma unroll
        for (int t = 0; t < 16; ++t) sums[t] += __shfl_down(sums[t], off);
    __shared__ float wred[4][16];
    if (lane == 0) {
#pragma unroll
        for (int t = 0; t < 16; ++t) wred[wave][t] = sums[t];
    }
    __syncthreads();
    if (tid < 16)
        xavg[row0 + tid] = (wred[0][tid] + wred[1][tid] + wred[2][tid] + wred[3][tid]) *
                           (1.f / DINNER);
}

// delta/B/C projections: thin GEMM (8192 x 48 x 2048), K split across waves.
__global__ __launch_bounds__(256) void dbc_direct(
    const u16* __restrict__ xconv, const u16* __restrict__ wcat,
    const float* __restrict__ db, const float* __restrict__ A_log,
    const float* __restrict__ xavg,
    float* __restrict__ a_out, float* __restrict__ u_out, float* __restrict__ c_out) {
    __shared__ float part[4][32][48];
    const int tid = threadIdx.x;
    const int lane = tid & 63;
    const int wave = tid >> 6;
    const int bm = blockIdx.x * 32;
    const int fr = lane & 15;
    const int kq = lane >> 4;
    const int k0 = wave * 512 + kq * 8;

    const u16* ap0 = xconv + (size_t)(bm + fr) * DINNER + k0;
    const u16* ap1 = xconv + (size_t)(bm + 16 + fr) * DINNER + k0;
    const u16* bp0 = wcat + (size_t)(fr) * DINNER + k0;
    const u16* bp1 = wcat + (size_t)(16 + fr) * DINNER + k0;
    const u16* bp2 = wcat + (size_t)(32 + fr) * DINNER + k0;

    floatx4 acc[2][3];
#pragma unroll
    for (int mi = 0; mi < 2; ++mi)
#pragma unroll
        for (int ni = 0; ni < 3; ++ni) acc[mi][ni] = (floatx4){0.f, 0.f, 0.f, 0.f};

#pragma unroll 4
    for (int kk = 0; kk < 16; ++kk) {
        short8 a0 = *(const short8*)ap0;
        short8 a1 = *(const short8*)ap1;
        short8 b0 = *(const short8*)bp0;
        short8 b1 = *(const short8*)bp1;
        short8 b2 = *(const short8*)bp2;
        ap0 += 32; ap1 += 32; bp0 += 32; bp1 += 32; bp2 += 32;
        acc[0][0] = __builtin_amdgcn_mfma_f32_16x16x32_bf16(a0, b0, acc[0][0], 0, 0, 0);
        acc[0][1] = __builtin_amdgcn_mfma_f32_16x16x32_bf16(a0, b1, acc[0][1], 0, 0, 0);
        acc[0][2] = __builtin_amdgcn_mfma_f32_16x16x32_bf16(a0, b2, acc[0][2], 0, 0, 0);
        acc[1][0] = __builtin_amdgcn_mfma_f32_16x16x32_bf16(a1, b0, acc[1][0], 0, 0, 0);
        acc[1][1] = __builtin_amdgcn_mfma_f32_16x16x32_bf16(a1, b1, acc[1][1], 0, 0, 0);
        acc[1][2] = __builtin_amdgcn_mfma_f32_16x16x32_bf16(a1, b2, acc[1][2], 0, 0, 0);
    }
    // C/D 16x16 layout: col = lane&15, row = (lane>>4)*4 + r
    const int cr = kq * 4;
#pragma unroll
    for (int mi = 0; mi < 2; ++mi)
#pragma unroll
        for (int ni = 0; ni < 3; ++ni)
#pragma unroll
            for (int r = 0; r < 4; ++r)
                part[wave][mi * 16 + cr + r][ni * 16 + fr] = acc[mi][ni][r];
    __syncthreads();
#pragma unroll
    for (int it = tid; it < 512; it += 256) {
        int row = it >> 4;
        int s = it & 15;
        float sd = 0.f, sb = 0.f, sc = 0.f;
#pragma unroll
        for (int w = 0; w < 4; ++w) {
            sd += part[w][row][s];
            sb += part[w][row][s + 16];
            sc += part[w][row][s + 32];
        }
        int grow = bm + row;
        float Aa = -__expf(A_log[s]);
        float pre = sd + db[s];
        float delta = (pre > 20.f) ? pre : log1pf(__expf(pre));
        a_out[grow * NSTATE + s] = __expf(delta * Aa);
        u_out[grow * NSTATE + s] = delta * sb * xavg[grow];
        c_out[grow * NSTATE + s] = sc;
    }
}

// ---- fused parallel linear scan: one kernel, 4 blocks (one per batch) ----
__global__ __launch_bounds__(1024) void scan_fused(
    const float* __restrict__ a, const float* __restrict__ u,
    const float* __restrict__ c, float* __restrict__ y) {
    const int b = blockIdx.x;
    const int tid = threadIdx.x;
    const int s = tid & 15;
    const int seg = tid >> 4;   // 0..63
    __shared__ float Ps[NSEG][NSTATE];
    __shared__ float Hs[NSEG][NSTATE];
    __shared__ float HSs[NSEG][NSTATE];

    size_t base = (size_t)(b * LL + seg * SEGLEN) * NSTATE + s;
    float P = 1.f, h = 0.f;
#pragma unroll 8
    for (int t = 0; t < SEGLEN; ++t) {
        float av = a[base + (size_t)t * NSTATE];
        float uv = u[base + (size_t)t * NSTATE];
        h = fmaf(av, h, uv);
        P *= av;
    }
    Ps[seg][s] = P;
    Hs[seg][s] = h;
    __syncthreads();
    if (tid < 16) {
        float hh = 0.f;
        for (int g = 0; g < NSEG; ++g) {
            HSs[g][tid] = hh;
            hh = fmaf(Ps[g][tid], hh, Hs[g][tid]);
        }
    }
    __syncthreads();
    float h2 = HSs[seg][s];
#pragma unroll 8
    for (int t = 0; t < SEGLEN; ++t) {
        float av = a[base + (size_t)t * NSTATE];
        float uv = u[base + (size_t)t * NSTATE];
        float cv = c[base + (size_t)t * NSTATE];
        h2 = fmaf(av, h2, uv);
        float p = h2 * cv;
        p += __shfl_xor(p, 1);
        p += __shfl_xor(p, 2);
        p += __shfl_xor(p, 4);
        p += __shfl_xor(p, 8);
        if (s == 0) y[b * LL + seg * SEGLEN + t] = p;
    }
}

// y_skip = y*silu(x_gate) + x_conv*D  -> bf16
__global__ __launch_bounds__(256) void gate_skip(
    const u16* __restrict__ xin, const float* __restrict__ y,
    const float* __restrict__ Dv, const u16* __restrict__ xconv,
    u16* __restrict__ yskip) {
    size_t i = ((size_t)blockIdx.x * 256 + threadIdx.x) * 8;
    int row = (int)(i >> 11);
    int d = (int)(i & (DINNER - 1));
    u16x8 g = *(const u16x8*)&xin[(size_t)row * (2 * DINNER) + DINNER + d];
    u16x8 xc = *(const u16x8*)&xconv[i];
    float yv = y[row];
    u16x8 o;
#pragma unroll
    for (int e = 0; e < 8; ++e) {
        float gv = silu_f(bf2f(g[e]));
        float v = yv * gv + bf2f(xc[e]) * Dv[d + e];
        o[e] = f2bf(v);
    }
    *(u16x8*)&yskip[i] = o;
}

extern "C" void kernel_launch(void* const* d_in, const int* in_sizes, int n_in,
                              void* d_out, int out_size, void* d_ws, size_t ws_size,
                              hipStream_t stream) {
    const float* x       = (const float*)d_in[0];
    const float* w_in    = (const float*)d_in[1];
    const float* conv_w  = (const float*)d_in[2];
    const float* conv_b  = (const float*)d_in[3];
    const float* A_log   = (const float*)d_in[4];
    const float* Dv      = (const float*)d_in[5];
    const float* delta_w = (const float*)d_in[6];
    const float* delta_b = (const float*)d_in[7];
    const float* B_w     = (const float*)d_in[8];
    const float* C_w     = (const float*)d_in[9];
    const float* out_w   = (const float*)d_in[10];
    float* out = (float*)d_out;

    u16* xb  = (u16*)d_ws;                 // 8192*1024
    u16* wb  = xb + 8388608;               // 4096*1024
    u16* owb = wb + 4194304;               // 1024*2048
    u16* wsb = owb + 2097152;              // 48*2048 (concat dw,bw,cw)
    u16* xin = wsb + 98304;                // 8192*4096
    u16* xcv = xin + 33554432;             // 8192*2048
    u16* ysk = xcv + 16777216;             // 8192*2048
    float* fb     = (float*)(ysk + 16777216);
    float* abuf   = fb;                    // 8192*16
    float* ubuf   = abuf + 131072;
    float* cbuf   = ubuf + 131072;
    float* ybuf   = cbuf + 131072;         // 8192
    float* avgbuf = ybuf + 8192;           // 8192

    cvt_multi<<<7216, 256, 0, stream>>>(x, w_in, out_w, delta_w, B_w, C_w,
                                        xb, wb, owb, wsb, wsb + 32768, wsb + 65536);

    // x_inner = x @ in_proj_w.T : (8192x1024)@(4096x1024)^T -> bf16
    gemm_bt_256<1><<<dim3(16, 32), 512, 0, stream>>>(xb, wb, xin, 2 * DINNER, DMODEL);

    conv_silu_avg<<<512, 256, 0, stream>>>(xin, conv_w, conv_b, xcv, avgbuf);
    dbc_direct<<<256, 256, 0, stream>>>(xcv, wsb, delta_b, A_log, avgbuf,
                                        abuf, ubuf, cbuf);

    scan_fused<<<4, 1024, 0, stream>>>(abuf, ubuf, cbuf, ybuf);

    gate_skip<<<NROW * DINNER / 8 / 256, 256, 0, stream>>>(xin, ybuf, Dv, xcv, ysk);

    // out = y_skip @ out_proj_w.T : (8192x2048)@(1024x2048)^T -> fp32
    gemm_bt_128p<0><<<dim3(8, 64), 512, 0, stream>>>(ysk, owb, out, DMODEL, DINNER);
}

// Round 9
// 295.171 us; speedup vs baseline: 1.0853x; 1.0618x over previous
//
#include <hip/hip_runtime.h>
#include <cmath>

#define LL 2048
#define NROW 8192
#define DMODEL 1024
#define DINNER 2048
#define NSTATE 16
#define NSEG 64
#define SEGLEN 32   // NSEG * SEGLEN == LL

typedef unsigned short u16;
typedef __attribute__((ext_vector_type(8))) unsigned short u16x8;
typedef __attribute__((ext_vector_type(8))) short short8;
typedef __attribute__((ext_vector_type(4))) float floatx4;
typedef __attribute__((ext_vector_type(16))) float floatx16;

__device__ __forceinline__ float bf2f(u16 h) {
    unsigned u = ((unsigned)h) << 16;
    float f;
    __builtin_memcpy(&f, &u, 4);
    return f;
}
__device__ __forceinline__ u16 f2bf(float f) {
    unsigned u;
    __builtin_memcpy(&u, &f, 4);
    u = u + 0x7fffu + ((u >> 16) & 1u);
    return (u16)(u >> 16);
}
__device__ __forceinline__ float silu_f(float x) { return x / (1.f + __expf(-x)); }

// One kernel converts all six fp32->bf16 tensors (2048 elems per block).
__global__ __launch_bounds__(256) void cvt_multi(
    const float* __restrict__ s0, const float* __restrict__ s1,
    const float* __restrict__ s2, const float* __restrict__ s3,
    const float* __restrict__ s4, const float* __restrict__ s5,
    u16* __restrict__ d0, u16* __restrict__ d1, u16* __restrict__ d2,
    u16* __restrict__ d3, u16* __restrict__ d4, u16* __restrict__ d5) {
    int bid = blockIdx.x;
    const float* s;
    u16* d;
    size_t off;
    if (bid < 4096)      { s = s0; d = d0; off = (size_t)bid * 2048; }
    else if (bid < 6144) { s = s1; d = d1; off = (size_t)(bid - 4096) * 2048; }
    else if (bid < 7168) { s = s2; d = d2; off = (size_t)(bid - 6144) * 2048; }
    else if (bid < 7184) { s = s3; d = d3; off = (size_t)(bid - 7168) * 2048; }
    else if (bid < 7200) { s = s4; d = d4; off = (size_t)(bid - 7184) * 2048; }
    else                 { s = s5; d = d5; off = (size_t)(bid - 7200) * 2048; }
    size_t i = off + (size_t)threadIdx.x * 8;
    float4 a = *(const float4*)&s[i];
    float4 b = *(const float4*)&s[i + 4];
    u16x8 o;
    o[0] = f2bf(a.x); o[1] = f2bf(a.y); o[2] = f2bf(a.z); o[3] = f2bf(a.w);
    o[4] = f2bf(b.x); o[5] = f2bf(b.y); o[6] = f2bf(b.z); o[7] = f2bf(b.w);
    *(u16x8*)&d[i] = o;
}

#define GL_LDS(gp, lp)                                                        \
    __builtin_amdgcn_global_load_lds(                                         \
        (const __attribute__((address_space(1))) void*)(gp),                  \
        (__attribute__((address_space(3))) void*)(lp), 16, 0, 0)
#define BAR() __builtin_amdgcn_s_barrier()
#define SB0() __builtin_amdgcn_sched_barrier(0)
#define LGKM0()                                                               \
    do {                                                                      \
        asm volatile("s_waitcnt lgkmcnt(0)" ::: "memory");                    \
        __builtin_amdgcn_sched_barrier(0);                                    \
    } while (0)
#define VMC4() asm volatile("s_waitcnt vmcnt(4)" ::: "memory")
#define VMC2() asm volatile("s_waitcnt vmcnt(2)" ::: "memory")
#define PRIO1() __builtin_amdgcn_s_setprio(1)
#define PRIO0() __builtin_amdgcn_s_setprio(0)

// ---------------------------------------------------------------------------
// 256x256 GEMM (C = A @ B^T), reads-after-MFMA pipelined 4-phase schedule.
// R6-VERIFIED VERBATIM (73.2 us, MfmaUtil 37%, 0 conflicts, WRITE 65.5 MB,
// no spill). R7 (full hoist) and R8 (partial hoist) both spilled and
// regressed -- any reorder extending a fragment's live range across an MFMA
// cluster breaks the 128-VGPR budget. Do not reschedule this kernel.
// ---------------------------------------------------------------------------
template <int OUT_BF16>
__global__ __launch_bounds__(512, 2) void gemm_bt_256(
    const u16* __restrict__ A, const u16* __restrict__ B,
    void* __restrict__ Cout, int N, int K) {
    __shared__ u16 sAf[2 * 2 * 128 * 64];   // [buf][half][row*64 + slot*8]
    __shared__ u16 sBf[2 * 2 * 128 * 64];
    const int tid = threadIdx.x;
    const int lane = tid & 63;
    const int wave = tid >> 6;   // 0..7
    const int wm = wave >> 2;    // 0..1
    const int wn = wave & 3;     // 0..3

    // XCD swizzle: linearize grid, chunk per XCD (nwg % 8 == 0 here).
    const int gx = gridDim.x;
    const int nwg = gx * gridDim.y;
    const int cpx = nwg >> 3;
    int lin = blockIdx.y * gx + blockIdx.x;
    int swz = (lin & 7) * cpx + (lin >> 3);
    const int bm = (swz / gx) * 256;
    const int bn = (swz % gx) * 256;

    // ---- staging addresses (pre-swizzled source k-slot) ----
    const int gslot = (lane & 7) ^ ((lane >> 3) & 7);
    const int srowoff = lane >> 3;                  // 0..7
    const u16* aStage = A + (size_t)(bm + wave * 8 + srowoff) * K + gslot * 8 + 64;
    const u16* bStage = B + (size_t)(bn + wave * 8 + srowoff) * K + gslot * 8 + 128;
    const size_t row64 = (size_t)64 * K;
    const size_t row128 = (size_t)128 * K;

#define STAGE_A(BUF, H, PTR)                                                  \
    do {                                                                      \
        GL_LDS((PTR) + (H) * row128,         &sAf[(BUF) * 16384 + (H) * 8192 + wave * 512]); \
        GL_LDS((PTR) + (H) * row128 + row64, &sAf[(BUF) * 16384 + (H) * 8192 + (8 + wave) * 512]); \
    } while (0)
#define STAGE_B(BUF, H, PTR)                                                  \
    do {                                                                      \
        GL_LDS((PTR) + (H) * row128,         &sBf[(BUF) * 16384 + (H) * 8192 + wave * 512]); \
        GL_LDS((PTR) + (H) * row128 + row64, &sBf[(BUF) * 16384 + (H) * 8192 + (8 + wave) * 512]); \
    } while (0)

    // ---- fragment read bases (element offsets) ----
    const int fr = lane & 15;
    const int kq = lane >> 4;
    const int st0 = kq ^ (fr & 7);
    const int st1 = (4 + kq) ^ (fr & 7);
    const int aRd0 = wm * 8192 + fr * 64 + st0 * 8;
    const int aRd1 = wm * 8192 + fr * 64 + st1 * 8;
    const int bRow = (wn & 1) * 64 + fr;
    const int bRd0 = (wn >> 1) * 8192 + bRow * 64 + st0 * 8;
    const int bRd1 = (wn >> 1) * 8192 + bRow * 64 + st1 * 8;

#define RD_A(dst, BUF, R0)                                                    \
    do {                                                                      \
        _Pragma("unroll")                                                     \
        for (int mi = 0; mi < 4; ++mi) {                                      \
            dst[mi][0] = *(const short8*)&sAf[(BUF) * 16384 + aRd0 + ((R0) + mi * 16) * 64]; \
            dst[mi][1] = *(const short8*)&sAf[(BUF) * 16384 + aRd1 + ((R0) + mi * 16) * 64]; \
        }                                                                     \
    } while (0)
#define RD_B(dst, BUF, R0)                                                    \
    do {                                                                      \
        _Pragma("unroll")                                                     \
        for (int ni = 0; ni < 2; ++ni) {                                      \
            dst[ni][0] = *(const short8*)&sBf[(BUF) * 16384 + bRd0 + ((R0) + ni * 16) * 64]; \
            dst[ni][1] = *(const short8*)&sBf[(BUF) * 16384 + bRd1 + ((R0) + ni * 16) * 64]; \
        }                                                                     \
    } while (0)
#define MFMA_PH(AF, RB, BF, CB)                                               \
    do {                                                                      \
        _Pragma("unroll")                                                     \
        for (int kh = 0; kh < 2; ++kh)                                        \
            _Pragma("unroll")                                                 \
            for (int mi = 0; mi < 4; ++mi)                                    \
                _Pragma("unroll")                                             \
                for (int ni = 0; ni < 2; ++ni)                                \
                    acc[(RB) + mi][(CB) + ni] =                               \
                        __builtin_amdgcn_mfma_f32_16x16x32_bf16(              \
                            AF[mi][kh], BF[ni][kh],                           \
                            acc[(RB) + mi][(CB) + ni], 0, 0, 0);              \
    } while (0)

    floatx4 acc[8][4];
#pragma unroll
    for (int i = 0; i < 8; ++i)
#pragma unroll
        for (int j = 0; j < 4; ++j) acc[i][j] = (floatx4){0.f, 0.f, 0.f, 0.f};

    short8 afX[4][2], afY[4][2], bf01[2][2], bf23[2][2];

    // ---- prologue: stage A(0),B(0),B(1); vmcnt(4) leaves B(1) in flight ----
    {
        const u16* a0 = aStage - 64;
        const u16* b0 = bStage - 128;
        STAGE_A(0, 0, a0);
        STAGE_A(0, 1, a0);
        STAGE_B(0, 0, b0);
        STAGE_B(0, 1, b0);
        STAGE_B(1, 0, b0 + 64);
        STAGE_B(1, 1, b0 + 64);
    }
    VMC4();
    BAR();
    RD_A(afX, 0, 0);
    RD_B(bf01, 0, 0);
    SB0();

// TILE body; CUR/NXT compile-time via x2 unroll. (R6 verbatim.)
#define TILE(CUR, NXT)                                                        \
    /* ph1: MFMA (qm0,n01); read bf23(cur); stage A0(t+1) */                  \
    LGKM0();                                                                  \
    PRIO1();                                                                  \
    MFMA_PH(afX, 0, bf01, 0);                                                 \
    PRIO0();                                                                  \
    SB0();                                                                    \
    RD_B(bf23, CUR, 32);                                                      \
    STAGE_A(NXT, 0, aStage);                                                  \
    SB0();                                                                    \
    /* ph2: MFMA (qm0,n23); read afY(cur); stage A1(t+1); mid sync */         \
    LGKM0();                                                                  \
    PRIO1();                                                                  \
    MFMA_PH(afX, 0, bf23, 2);                                                 \
    PRIO0();                                                                  \
    SB0();                                                                    \
    RD_A(afY, CUR, 64);                                                       \
    STAGE_A(NXT, 1, aStage);                                                  \
    VMC4(); /* B(t+1) landed */                                               \
    BAR();                                                                    \
    /* ph3: MFMA (qm1,n01); read bf01'(nxt); stage B0(t+2) */                 \
    LGKM0();                                                                  \
    PRIO1();                                                                  \
    MFMA_PH(afY, 4, bf01, 0);                                                 \
    PRIO0();                                                                  \
    SB0();                                                                    \
    RD_B(bf01, NXT, 0);                                                       \
    STAGE_B(CUR, 0, bStage);                                                  \
    SB0();                                                                    \
    /* ph4: MFMA (qm1,n23); stage B1(t+2); end sync; read afX' */             \
    PRIO1();                                                                  \
    MFMA_PH(afY, 4, bf23, 2);                                                 \
    PRIO0();                                                                  \
    SB0();                                                                    \
    STAGE_B(CUR, 1, bStage);                                                  \
    VMC4(); /* A(t+1) landed */                                               \
    BAR();                                                                    \
    RD_A(afX, NXT, 0);                                                        \
    SB0();                                                                    \
    aStage += 64;                                                             \
    bStage += 64;

    const int NT = K >> 6;  // even (16 here)
    for (int t = 0; t < NT; t += 2) {
        TILE(0, 1)
        TILE(1, 0)
    }
#undef TILE

    // epilogue: C/D 16x16 layout: col = lane&15, row = (lane>>4)*4 + r
    const int cc = lane & 15;
    const int rb = (lane >> 4) * 4;
#pragma unroll
    for (int mi = 0; mi < 8; ++mi)
#pragma unroll
        for (int ni = 0; ni < 4; ++ni)
#pragma unroll
            for (int r = 0; r < 4; ++r) {
                int grow = bm + wm * 128 + mi * 16 + rb + r;
                int gcol = bn + wn * 64 + ni * 16 + cc;
                float v = acc[mi][ni][r];
                if (OUT_BF16)
                    ((u16*)Cout)[(size_t)grow * N + gcol] = f2bf(v);
                else
                    ((float*)Cout)[(size_t)grow * N + gcol] = v;
            }
#undef STAGE_A
#undef STAGE_B
#undef RD_A
#undef RD_B
#undef MFMA_PH
}

// ---------------------------------------------------------------------------
// 128x128 GEMM (C = A @ B^T), pipelined schedule at 128-tile for the thin
// out-proj (N=1024 -> 512 blocks). BK=64, 8 waves (2M x 4N), per-wave C =
// 64x32. LDS 64 KiB dbuf -> 2 blocks/CU (4 waves/SIMD). 2 phases/tile,
// 2 barriers, counted vmcnt(2). R6-VERIFIED VERBATIM.
// ---------------------------------------------------------------------------
template <int OUT_BF16>
__global__ __launch_bounds__(512, 4) void gemm_bt_128p(
    const u16* __restrict__ A, const u16* __restrict__ B,
    void* __restrict__ Cout, int N, int K) {
    __shared__ u16 sAf[2 * 128 * 64];   // [buf][row*64 + slot*8]
    __shared__ u16 sBf[2 * 128 * 64];
    const int tid = threadIdx.x;
    const int lane = tid & 63;
    const int wave = tid >> 6;   // 0..7
    const int wm = wave >> 2;    // 0..1  (M half: 64 rows)
    const int wn = wave & 3;     // 0..3  (N quarter: 32 cols)

    const int gx = gridDim.x;
    const int nwg = gx * gridDim.y;
    const int cpx = nwg >> 3;                       // nwg % 8 == 0 here
    int lin = blockIdx.y * gx + blockIdx.x;
    int swz = (lin & 7) * cpx + (lin >> 3);
    const int bm = (swz / gx) * 128;
    const int bn = (swz % gx) * 128;

    const int gslot = (lane & 7) ^ ((lane >> 3) & 7);
    const int srowoff = lane >> 3;                  // 0..7
    const u16* aStage = A + (size_t)(bm + wave * 8 + srowoff) * K + gslot * 8 + 64;
    const u16* bStage = B + (size_t)(bn + wave * 8 + srowoff) * K + gslot * 8 + 128;
    const size_t row64 = (size_t)64 * K;

#define STAGE_A(BUF, PTR)                                                     \
    do {                                                                      \
        GL_LDS((PTR),         &sAf[(BUF) * 8192 + wave * 512]);               \
        GL_LDS((PTR) + row64, &sAf[(BUF) * 8192 + (8 + wave) * 512]);         \
    } while (0)
#define STAGE_B(BUF, PTR)                                                     \
    do {                                                                      \
        GL_LDS((PTR),         &sBf[(BUF) * 8192 + wave * 512]);               \
        GL_LDS((PTR) + row64, &sBf[(BUF) * 8192 + (8 + wave) * 512]);         \
    } while (0)

    const int fr = lane & 15;
    const int kq = lane >> 4;
    const int st0 = kq ^ (fr & 7);
    const int st1 = (4 + kq) ^ (fr & 7);
    const int aRd0 = (wm * 64 + fr) * 64 + st0 * 8;
    const int aRd1 = (wm * 64 + fr) * 64 + st1 * 8;
    const int bRd0 = (wn * 32 + fr) * 64 + st0 * 8;
    const int bRd1 = (wn * 32 + fr) * 64 + st1 * 8;

#define RD_A(dst, BUF)                                                        \
    do {                                                                      \
        _Pragma("unroll")                                                     \
        for (int mi = 0; mi < 4; ++mi) {                                      \
            dst[mi][0] = *(const short8*)&sAf[(BUF) * 8192 + aRd0 + mi * 16 * 64]; \
            dst[mi][1] = *(const short8*)&sAf[(BUF) * 8192 + aRd1 + mi * 16 * 64]; \
        }                                                                     \
    } while (0)
#define RD_B(dst, BUF, NI)                                                    \
    do {                                                                      \
        dst[0] = *(const short8*)&sBf[(BUF) * 8192 + bRd0 + (NI) * 16 * 64];  \
        dst[1] = *(const short8*)&sBf[(BUF) * 8192 + bRd1 + (NI) * 16 * 64];  \
    } while (0)
#define MFMA8(BF, NI)                                                         \
    do {                                                                      \
        _Pragma("unroll")                                                     \
        for (int kh = 0; kh < 2; ++kh)                                        \
            _Pragma("unroll")                                                 \
            for (int mi = 0; mi < 4; ++mi)                                    \
                acc[mi][NI] = __builtin_amdgcn_mfma_f32_16x16x32_bf16(        \
                    afc[mi][kh], BF[kh], acc[mi][NI], 0, 0, 0);               \
    } while (0)

    floatx4 acc[4][2];
#pragma unroll
    for (int i = 0; i < 4; ++i)
#pragma unroll
        for (int j = 0; j < 2; ++j) acc[i][j] = (floatx4){0.f, 0.f, 0.f, 0.f};

    short8 afc[4][2], bf0[2], bf1[2];

    STAGE_A(0, aStage - 64);
    STAGE_B(0, bStage - 128);
    STAGE_B(1, bStage - 64);
    VMC2();
    BAR();
    RD_A(afc, 0);
    RD_B(bf0, 0, 0);
    SB0();

#define TILE(CUR, NXT)                                                        \
    LGKM0();                                                                  \
    PRIO1();                                                                  \
    MFMA8(bf0, 0);                                                            \
    PRIO0();                                                                  \
    SB0();                                                                    \
    RD_B(bf1, CUR, 1);                                                        \
    STAGE_A(NXT, aStage);                                                     \
    BAR();                                                                    \
    LGKM0();                                                                  \
    PRIO1();                                                                  \
    MFMA8(bf1, 1);                                                            \
    PRIO0();                                                                  \
    SB0();                                                                    \
    STAGE_B(CUR, bStage);                                                     \
    VMC2(); /* A(t+1), B(t+1) landed; B(t+2) in flight */                     \
    BAR();                                                                    \
    RD_A(afc, NXT);                                                           \
    RD_B(bf0, NXT, 0);                                                        \
    SB0();                                                                    \
    aStage += 64;                                                             \
    bStage += 64;

    const int NT = K >> 6;  // 32 here (even)
    for (int t = 0; t < NT; t += 2) {
        TILE(0, 1)
        TILE(1, 0)
    }
#undef TILE

    asm volatile("s_waitcnt vmcnt(0)" ::: "memory");  // drain overrun stages

    const int cc = lane & 15;
    const int rb = (lane >> 4) * 4;
#pragma unroll
    for (int mi = 0; mi < 4; ++mi)
#pragma unroll
        for (int ni = 0; ni < 2; ++ni)
#pragma unroll
            for (int r = 0; r < 4; ++r) {
                int grow = bm + wm * 64 + mi * 16 + rb + r;
                int gcol = bn + wn * 32 + ni * 16 + cc;
                float v = acc[mi][ni][r];
                if (OUT_BF16)
                    ((u16*)Cout)[(size_t)grow * N + gcol] = f2bf(v);
                else
                    ((float*)Cout)[(size_t)grow * N + gcol] = v;
            }
#undef STAGE_A
#undef STAGE_B
#undef RD_A
#undef RD_B
#undef MFMA8
}

// ---------------------------------------------------------------------------
// FUSED: depthwise causal conv (DC=4) + bias + silu + row-mean + delta/B/C
// projections + scan-input prep. 512 blocks x 16 rows x 256 threads.
// Conv part identical to the verified conv_silu_avg; additionally keeps the
// 16x2048 xconv tile in LDS (padded stride 2056 elems so A-frag reads are
// not systematically same-bank). dbc part = dbc_direct's verified math with
// A sourced from LDS instead of global (same fragment maps, same wave
// K-split: wave w covers k in [w*512, w*512+512)), B/weights from global
// (192 KB, L2-resident). Partials reduced via LDS; epilogue = 256 threads
// = 16 rows x 16 states. Eliminates dbc_direct's dispatch + 33.5 MB xcv
// re-read; xavg stays in LDS (no global xavg buffer).
// LDS: 65792 + 12288 + 256 + 64 = 78.4 KB -> 2 blocks/CU (grid = 2/CU).
// ---------------------------------------------------------------------------
#define XT_STRIDE 2056
__global__ __launch_bounds__(256) void conv_dbc(
    const u16* __restrict__ xin, const float* __restrict__ cw,
    const float* __restrict__ cb, const u16* __restrict__ wcat,
    const float* __restrict__ db, const float* __restrict__ A_log,
    u16* __restrict__ xconv,
    float* __restrict__ a_out, float* __restrict__ u_out,
    float* __restrict__ c_out) {
    __shared__ u16 xtile[16 * XT_STRIDE];
    __shared__ float part[4][16][48];
    __shared__ float wred[4][16];
    __shared__ float xa[16];
    const int blk = blockIdx.x;        // 512 blocks
    const int b = blk >> 7;
    const int lc = blk & 127;
    const int row0 = b * LL + lc * 16;
    const int tid = threadIdx.x;
    const int lane = tid & 63, wave = tid >> 6;
    const int d0 = tid * 8;

    // ---- conv + silu + tile stash (verified conv_silu_avg body) ----
    float4 cwv[8];
    float cbv[8];
#pragma unroll
    for (int e = 0; e < 8; ++e) cwv[e] = *(const float4*)&cw[(d0 + e) * 4];
#pragma unroll
    for (int e = 0; e < 8; e += 4) {
        float4 c = *(const float4*)&cb[d0 + e];
        cbv[e] = c.x; cbv[e + 1] = c.y; cbv[e + 2] = c.z; cbv[e + 3] = c.w;
    }
    u16x8 w0, w1, w2;
    if (lc == 0) {
        w0 = (u16x8)0; w1 = (u16x8)0; w2 = (u16x8)0;
    } else {
        w0 = *(const u16x8*)&xin[(size_t)(row0 - 3) * (2 * DINNER) + d0];
        w1 = *(const u16x8*)&xin[(size_t)(row0 - 2) * (2 * DINNER) + d0];
        w2 = *(const u16x8*)&xin[(size_t)(row0 - 1) * (2 * DINNER) + d0];
    }
    float sums[16];
#pragma unroll
    for (int t = 0; t < 16; ++t) {
        u16x8 cur = *(const u16x8*)&xin[(size_t)(row0 + t) * (2 * DINNER) + d0];
        float lsum = 0.f;
        u16x8 o;
#pragma unroll
        for (int e = 0; e < 8; ++e) {
            float acc = cbv[e];
            acc += bf2f(w0[e]) * cwv[e].x;
            acc += bf2f(w1[e]) * cwv[e].y;
            acc += bf2f(w2[e]) * cwv[e].z;
            acc += bf2f(cur[e]) * cwv[e].w;
            float s = silu_f(acc);
            lsum += s;
            o[e] = f2bf(s);
        }
        *(u16x8*)&xconv[(size_t)(row0 + t) * DINNER + d0] = o;
        *(u16x8*)&xtile[t * XT_STRIDE + d0] = o;
        sums[t] = lsum;
        w0 = w1; w1 = w2; w2 = cur;
    }
#pragma unroll
    for (int off = 32; off; off >>= 1)
#pragma unroll
        for (int t = 0; t < 16; ++t) sums[t] += __shfl_down(sums[t], off);
    if (lane == 0) {
#pragma unroll
        for (int t = 0; t < 16; ++t) wred[wave][t] = sums[t];
    }
    __syncthreads();
    if (tid < 16)
        xa[tid] = (wred[0][tid] + wred[1][tid] + wred[2][tid] + wred[3][tid]) *
                  (1.f / DINNER);
    __syncthreads();   // xtile + xa visible to all waves

    // ---- dbc projection (dbc_direct math; A from LDS) ----
    const int fr = lane & 15;
    const int kq = lane >> 4;
    const int k0 = wave * 512 + kq * 8;
    const u16* bp0 = wcat + (size_t)fr * DINNER + k0;
    const u16* bp1 = wcat + (size_t)(16 + fr) * DINNER + k0;
    const u16* bp2 = wcat + (size_t)(32 + fr) * DINNER + k0;
    const int aBase = fr * XT_STRIDE + k0;

    floatx4 pacc[3];
#pragma unroll
    for (int ni = 0; ni < 3; ++ni) pacc[ni] = (floatx4){0.f, 0.f, 0.f, 0.f};

#pragma unroll 4
    for (int kk = 0; kk < 16; ++kk) {
        short8 a0 = *(const short8*)&xtile[aBase + kk * 32];
        short8 b0 = *(const short8*)(bp0 + kk * 32);
        short8 b1 = *(const short8*)(bp1 + kk * 32);
        short8 b2 = *(const short8*)(bp2 + kk * 32);
        pacc[0] = __builtin_amdgcn_mfma_f32_16x16x32_bf16(a0, b0, pacc[0], 0, 0, 0);
        pacc[1] = __builtin_amdgcn_mfma_f32_16x16x32_bf16(a0, b1, pacc[1], 0, 0, 0);
        pacc[2] = __builtin_amdgcn_mfma_f32_16x16x32_bf16(a0, b2, pacc[2], 0, 0, 0);
    }
    // C/D 16x16 layout: col = lane&15 (weight row), row = (lane>>4)*4 + r
    const int cr = kq * 4;
#pragma unroll
    for (int ni = 0; ni < 3; ++ni)
#pragma unroll
        for (int r = 0; r < 4; ++r)
            part[wave][cr + r][ni * 16 + fr] = pacc[ni][r];
    __syncthreads();

    // epilogue: 256 threads = 16 rows x 16 states
    {
        int row = tid >> 4;
        int s = tid & 15;
        float sd = part[0][row][s] + part[1][row][s] + part[2][row][s] + part[3][row][s];
        float sb = part[0][row][s + 16] + part[1][row][s + 16] +
                   part[2][row][s + 16] + part[3][row][s + 16];
        float sc = part[0][row][s + 32] + part[1][row][s + 32] +
                   part[2][row][s + 32] + part[3][row][s + 32];
        int grow = row0 + row;
        float Aa = -__expf(A_log[s]);
        float pre = sd + db[s];
        float delta = (pre > 20.f) ? pre : log1pf(__expf(pre));
        a_out[grow * NSTATE + s] = __expf(delta * Aa);
        u_out[grow * NSTATE + s] = delta * sb * xa[row];
        c_out[grow * NSTATE + s] = sc;
    }
}

// ---- fused parallel linear scan: one kernel, 4 blocks (one per batch) ----
__global__ __launch_bounds__(1024) void scan_fused(
    const float* __restrict__ a, const float* __restrict__ u,
    const float* __restrict__ c, float* __restrict__ y) {
    const int b = blockIdx.x;
    const int tid = threadIdx.x;
    const int s = tid & 15;
    const int seg = tid >> 4;   // 0..63
    __shared__ float Ps[NSEG][NSTATE];
    __shared__ float Hs[NSEG][NSTATE];
    __shared__ float HSs[NSEG][NSTATE];

    size_t base = (size_t)(b * LL + seg * SEGLEN) * NSTATE + s;
    float P = 1.f, h = 0.f;
#pragma unroll 8
    for (int t = 0; t < SEGLEN; ++t) {
        float av = a[base + (size_t)t * NSTATE];
        float uv = u[base + (size_t)t * NSTATE];
        h = fmaf(av, h, uv);
        P *= av;
    }
    Ps[seg][s] = P;
    Hs[seg][s] = h;
    __syncthreads();
    if (tid < 16) {
        float hh = 0.f;
        for (int g = 0; g < NSEG; ++g) {
            HSs[g][tid] = hh;
            hh = fmaf(Ps[g][tid], hh, Hs[g][tid]);
        }
    }
    __syncthreads();
    float h2 = HSs[seg][s];
#pragma unroll 8
    for (int t = 0; t < SEGLEN; ++t) {
        float av = a[base + (size_t)t * NSTATE];
        float uv = u[base + (size_t)t * NSTATE];
        float cv = c[base + (size_t)t * NSTATE];
        h2 = fmaf(av, h2, uv);
        float p = h2 * cv;
        p += __shfl_xor(p, 1);
        p += __shfl_xor(p, 2);
        p += __shfl_xor(p, 4);
        p += __shfl_xor(p, 8);
        if (s == 0) y[b * LL + seg * SEGLEN + t] = p;
    }
}

// y_skip = y*silu(x_gate) + x_conv*D  -> bf16
__global__ __launch_bounds__(256) void gate_skip(
    const u16* __restrict__ xin, const float* __restrict__ y,
    const float* __restrict__ Dv, const u16* __restrict__ xconv,
    u16* __restrict__ yskip) {
    size_t i = ((size_t)blockIdx.x * 256 + threadIdx.x) * 8;
    int row = (int)(i >> 11);
    int d = (int)(i & (DINNER - 1));
    u16x8 g = *(const u16x8*)&xin[(size_t)row * (2 * DINNER) + DINNER + d];
    u16x8 xc = *(const u16x8*)&xconv[i];
    float yv = y[row];
    u16x8 o;
#pragma unroll
    for (int e = 0; e < 8; ++e) {
        float gv = silu_f(bf2f(g[e]));
        float v = yv * gv + bf2f(xc[e]) * Dv[d + e];
        o[e] = f2bf(v);
    }
    *(u16x8*)&yskip[i] = o;
}

extern "C" void kernel_launch(void* const* d_in, const int* in_sizes, int n_in,
                              void* d_out, int out_size, void* d_ws, size_t ws_size,
                              hipStream_t stream) {
    const float* x       = (const float*)d_in[0];
    const float* w_in    = (const float*)d_in[1];
    const float* conv_w  = (const float*)d_in[2];
    const float* conv_b  = (const float*)d_in[3];
    const float* A_log   = (const float*)d_in[4];
    const float* Dv      = (const float*)d_in[5];
    const float* delta_w = (const float*)d_in[6];
    const float* delta_b = (const float*)d_in[7];
    const float* B_w     = (const float*)d_in[8];
    const float* C_w     = (const float*)d_in[9];
    const float* out_w   = (const float*)d_in[10];
    float* out = (float*)d_out;

    u16* xb  = (u16*)d_ws;                 // 8192*1024
    u16* wb  = xb + 8388608;               // 4096*1024
    u16* owb = wb + 4194304;               // 1024*2048
    u16* wsb = owb + 2097152;              // 48*2048 (concat dw,bw,cw)
    u16* xin = wsb + 98304;                // 8192*4096
    u16* xcv = xin + 33554432;             // 8192*2048
    u16* ysk = xcv + 16777216;             // 8192*2048
    float* fb     = (float*)(ysk + 16777216);
    float* abuf   = fb;                    // 8192*16
    float* ubuf   = abuf + 131072;
    float* cbuf   = ubuf + 131072;
    float* ybuf   = cbuf + 131072;         // 8192

    cvt_multi<<<7216, 256, 0, stream>>>(x, w_in, out_w, delta_w, B_w, C_w,
                                        xb, wb, owb, wsb, wsb + 32768, wsb + 65536);

    // x_inner = x @ in_proj_w.T : (8192x1024)@(4096x1024)^T -> bf16
    gemm_bt_256<1><<<dim3(16, 32), 512, 0, stream>>>(xb, wb, xin, 2 * DINNER, DMODEL);

    // conv + silu + mean + delta/B/C projections (fused)
    conv_dbc<<<512, 256, 0, stream>>>(xin, conv_w, conv_b, wsb, delta_b, A_log,
                                      xcv, abuf, ubuf, cbuf);

    scan_fused<<<4, 1024, 0, stream>>>(abuf, ubuf, cbuf, ybuf);

    gate_skip<<<NROW * DINNER / 8 / 256, 256, 0, stream>>>(xin, ybuf, Dv, xcv, ysk);

    // out = y_skip @ out_proj_w.T : (8192x2048)@(1024x2048)^T -> fp32
    gemm_bt_128p<0><<<dim3(8, 64), 512, 0, stream>>>(ysk, owb, out, DMODEL, DINNER);
}

// Round 10
// 284.784 us; speedup vs baseline: 1.1249x; 1.0365x over previous
//
#include <hip/hip_runtime.h>
#include <cmath>

#define LL 2048
#define NROW 8192
#define DMODEL 1024
#define DINNER 2048
#define NSTATE 16
#define NSEG 64
#define SEGLEN 32   // NSEG * SEGLEN == LL

typedef unsigned short u16;
typedef __attribute__((ext_vector_type(8))) unsigned short u16x8;
typedef __attribute__((ext_vector_type(8))) short short8;
typedef __attribute__((ext_vector_type(4))) float floatx4;
typedef __attribute__((ext_vector_type(16))) float floatx16;

__device__ __forceinline__ float bf2f(u16 h) {
    unsigned u = ((unsigned)h) << 16;
    float f;
    __builtin_memcpy(&f, &u, 4);
    return f;
}
__device__ __forceinline__ u16 f2bf(float f) {
    unsigned u;
    __builtin_memcpy(&u, &f, 4);
    u = u + 0x7fffu + ((u >> 16) & 1u);
    return (u16)(u >> 16);
}
__device__ __forceinline__ float silu_f(float x) { return x / (1.f + __expf(-x)); }

// One kernel converts all six fp32->bf16 tensors (2048 elems per block).
__global__ __launch_bounds__(256) void cvt_multi(
    const float* __restrict__ s0, const float* __restrict__ s1,
    const float* __restrict__ s2, const float* __restrict__ s3,
    const float* __restrict__ s4, const float* __restrict__ s5,
    u16* __restrict__ d0, u16* __restrict__ d1, u16* __restrict__ d2,
    u16* __restrict__ d3, u16* __restrict__ d4, u16* __restrict__ d5) {
    int bid = blockIdx.x;
    const float* s;
    u16* d;
    size_t off;
    if (bid < 4096)      { s = s0; d = d0; off = (size_t)bid * 2048; }
    else if (bid < 6144) { s = s1; d = d1; off = (size_t)(bid - 4096) * 2048; }
    else if (bid < 7168) { s = s2; d = d2; off = (size_t)(bid - 6144) * 2048; }
    else if (bid < 7184) { s = s3; d = d3; off = (size_t)(bid - 7168) * 2048; }
    else if (bid < 7200) { s = s4; d = d4; off = (size_t)(bid - 7184) * 2048; }
    else                 { s = s5; d = d5; off = (size_t)(bid - 7200) * 2048; }
    size_t i = off + (size_t)threadIdx.x * 8;
    float4 a = *(const float4*)&s[i];
    float4 b = *(const float4*)&s[i + 4];
    u16x8 o;
    o[0] = f2bf(a.x); o[1] = f2bf(a.y); o[2] = f2bf(a.z); o[3] = f2bf(a.w);
    o[4] = f2bf(b.x); o[5] = f2bf(b.y); o[6] = f2bf(b.z); o[7] = f2bf(b.w);
    *(u16x8*)&d[i] = o;
}

#define GL_LDS(gp, lp)                                                        \
    __builtin_amdgcn_global_load_lds(                                         \
        (const __attribute__((address_space(1))) void*)(gp),                  \
        (__attribute__((address_space(3))) void*)(lp), 16, 0, 0)
#define BAR() __builtin_amdgcn_s_barrier()
#define SB0() __builtin_amdgcn_sched_barrier(0)
#define LGKM0()                                                               \
    do {                                                                      \
        asm volatile("s_waitcnt lgkmcnt(0)" ::: "memory");                    \
        __builtin_amdgcn_sched_barrier(0);                                    \
    } while (0)
#define VMC4() asm volatile("s_waitcnt vmcnt(4)" ::: "memory")
#define VMC2() asm volatile("s_waitcnt vmcnt(2)" ::: "memory")
#define PRIO1() __builtin_amdgcn_s_setprio(1)
#define PRIO0() __builtin_amdgcn_s_setprio(0)

// ---------------------------------------------------------------------------
// 256x256 GEMM (C = A @ B^T), reads-after-MFMA pipelined 4-phase schedule.
// R6-VERIFIED VERBATIM (73.2 us, MfmaUtil 37%, 0 conflicts, WRITE 65.5 MB,
// no spill). R7 (full hoist) and R8 (partial hoist) both spilled and
// regressed -- any reorder extending a fragment's live range across an MFMA
// cluster breaks the 128-VGPR budget. Do not reschedule this kernel.
// ---------------------------------------------------------------------------
template <int OUT_BF16>
__global__ __launch_bounds__(512, 2) void gemm_bt_256(
    const u16* __restrict__ A, const u16* __restrict__ B,
    void* __restrict__ Cout, int N, int K) {
    __shared__ u16 sAf[2 * 2 * 128 * 64];   // [buf][half][row*64 + slot*8]
    __shared__ u16 sBf[2 * 2 * 128 * 64];
    const int tid = threadIdx.x;
    const int lane = tid & 63;
    const int wave = tid >> 6;   // 0..7
    const int wm = wave >> 2;    // 0..1
    const int wn = wave & 3;     // 0..3

    // XCD swizzle: linearize grid, chunk per XCD (nwg % 8 == 0 here).
    const int gx = gridDim.x;
    const int nwg = gx * gridDim.y;
    const int cpx = nwg >> 3;
    int lin = blockIdx.y * gx + blockIdx.x;
    int swz = (lin & 7) * cpx + (lin >> 3);
    const int bm = (swz / gx) * 256;
    const int bn = (swz % gx) * 256;

    // ---- staging addresses (pre-swizzled source k-slot) ----
    const int gslot = (lane & 7) ^ ((lane >> 3) & 7);
    const int srowoff = lane >> 3;                  // 0..7
    const u16* aStage = A + (size_t)(bm + wave * 8 + srowoff) * K + gslot * 8 + 64;
    const u16* bStage = B + (size_t)(bn + wave * 8 + srowoff) * K + gslot * 8 + 128;
    const size_t row64 = (size_t)64 * K;
    const size_t row128 = (size_t)128 * K;

#define STAGE_A(BUF, H, PTR)                                                  \
    do {                                                                      \
        GL_LDS((PTR) + (H) * row128,         &sAf[(BUF) * 16384 + (H) * 8192 + wave * 512]); \
        GL_LDS((PTR) + (H) * row128 + row64, &sAf[(BUF) * 16384 + (H) * 8192 + (8 + wave) * 512]); \
    } while (0)
#define STAGE_B(BUF, H, PTR)                                                  \
    do {                                                                      \
        GL_LDS((PTR) + (H) * row128,         &sBf[(BUF) * 16384 + (H) * 8192 + wave * 512]); \
        GL_LDS((PTR) + (H) * row128 + row64, &sBf[(BUF) * 16384 + (H) * 8192 + (8 + wave) * 512]); \
    } while (0)

    // ---- fragment read bases (element offsets) ----
    const int fr = lane & 15;
    const int kq = lane >> 4;
    const int st0 = kq ^ (fr & 7);
    const int st1 = (4 + kq) ^ (fr & 7);
    const int aRd0 = wm * 8192 + fr * 64 + st0 * 8;
    const int aRd1 = wm * 8192 + fr * 64 + st1 * 8;
    const int bRow = (wn & 1) * 64 + fr;
    const int bRd0 = (wn >> 1) * 8192 + bRow * 64 + st0 * 8;
    const int bRd1 = (wn >> 1) * 8192 + bRow * 64 + st1 * 8;

#define RD_A(dst, BUF, R0)                                                    \
    do {                                                                      \
        _Pragma("unroll")                                                     \
        for (int mi = 0; mi < 4; ++mi) {                                      \
            dst[mi][0] = *(const short8*)&sAf[(BUF) * 16384 + aRd0 + ((R0) + mi * 16) * 64]; \
            dst[mi][1] = *(const short8*)&sAf[(BUF) * 16384 + aRd1 + ((R0) + mi * 16) * 64]; \
        }                                                                     \
    } while (0)
#define RD_B(dst, BUF, R0)                                                    \
    do {                                                                      \
        _Pragma("unroll")                                                     \
        for (int ni = 0; ni < 2; ++ni) {                                      \
            dst[ni][0] = *(const short8*)&sBf[(BUF) * 16384 + bRd0 + ((R0) + ni * 16) * 64]; \
            dst[ni][1] = *(const short8*)&sBf[(BUF) * 16384 + bRd1 + ((R0) + ni * 16) * 64]; \
        }                                                                     \
    } while (0)
#define MFMA_PH(AF, RB, BF, CB)                                               \
    do {                                                                      \
        _Pragma("unroll")                                                     \
        for (int kh = 0; kh < 2; ++kh)                                        \
            _Pragma("unroll")                                                 \
            for (int mi = 0; mi < 4; ++mi)                                    \
                _Pragma("unroll")                                             \
                for (int ni = 0; ni < 2; ++ni)                                \
                    acc[(RB) + mi][(CB) + ni] =                               \
                        __builtin_amdgcn_mfma_f32_16x16x32_bf16(              \
                            AF[mi][kh], BF[ni][kh],                           \
                            acc[(RB) + mi][(CB) + ni], 0, 0, 0);              \
    } while (0)

    floatx4 acc[8][4];
#pragma unroll
    for (int i = 0; i < 8; ++i)
#pragma unroll
        for (int j = 0; j < 4; ++j) acc[i][j] = (floatx4){0.f, 0.f, 0.f, 0.f};

    short8 afX[4][2], afY[4][2], bf01[2][2], bf23[2][2];

    // ---- prologue: stage A(0),B(0),B(1); vmcnt(4) leaves B(1) in flight ----
    {
        const u16* a0 = aStage - 64;
        const u16* b0 = bStage - 128;
        STAGE_A(0, 0, a0);
        STAGE_A(0, 1, a0);
        STAGE_B(0, 0, b0);
        STAGE_B(0, 1, b0);
        STAGE_B(1, 0, b0 + 64);
        STAGE_B(1, 1, b0 + 64);
    }
    VMC4();
    BAR();
    RD_A(afX, 0, 0);
    RD_B(bf01, 0, 0);
    SB0();

// TILE body; CUR/NXT compile-time via x2 unroll. (R6 verbatim.)
#define TILE(CUR, NXT)                                                        \
    /* ph1: MFMA (qm0,n01); read bf23(cur); stage A0(t+1) */                  \
    LGKM0();                                                                  \
    PRIO1();                                                                  \
    MFMA_PH(afX, 0, bf01, 0);                                                 \
    PRIO0();                                                                  \
    SB0();                                                                    \
    RD_B(bf23, CUR, 32);                                                      \
    STAGE_A(NXT, 0, aStage);                                                  \
    SB0();                                                                    \
    /* ph2: MFMA (qm0,n23); read afY(cur); stage A1(t+1); mid sync */         \
    LGKM0();                                                                  \
    PRIO1();                                                                  \
    MFMA_PH(afX, 0, bf23, 2);                                                 \
    PRIO0();                                                                  \
    SB0();                                                                    \
    RD_A(afY, CUR, 64);                                                       \
    STAGE_A(NXT, 1, aStage);                                                  \
    VMC4(); /* B(t+1) landed */                                               \
    BAR();                                                                    \
    /* ph3: MFMA (qm1,n01); read bf01'(nxt); stage B0(t+2) */                 \
    LGKM0();                                                                  \
    PRIO1();                                                                  \
    MFMA_PH(afY, 4, bf01, 0);                                                 \
    PRIO0();                                                                  \
    SB0();                                                                    \
    RD_B(bf01, NXT, 0);                                                       \
    STAGE_B(CUR, 0, bStage);                                                  \
    SB0();                                                                    \
    /* ph4: MFMA (qm1,n23); stage B1(t+2); end sync; read afX' */             \
    PRIO1();                                                                  \
    MFMA_PH(afY, 4, bf23, 2);                                                 \
    PRIO0();                                                                  \
    SB0();                                                                    \
    STAGE_B(CUR, 1, bStage);                                                  \
    VMC4(); /* A(t+1) landed */                                               \
    BAR();                                                                    \
    RD_A(afX, NXT, 0);                                                        \
    SB0();                                                                    \
    aStage += 64;                                                             \
    bStage += 64;

    const int NT = K >> 6;  // even (16 here)
    for (int t = 0; t < NT; t += 2) {
        TILE(0, 1)
        TILE(1, 0)
    }
#undef TILE

    // epilogue: C/D 16x16 layout: col = lane&15, row = (lane>>4)*4 + r
    const int cc = lane & 15;
    const int rb = (lane >> 4) * 4;
#pragma unroll
    for (int mi = 0; mi < 8; ++mi)
#pragma unroll
        for (int ni = 0; ni < 4; ++ni)
#pragma unroll
            for (int r = 0; r < 4; ++r) {
                int grow = bm + wm * 128 + mi * 16 + rb + r;
                int gcol = bn + wn * 64 + ni * 16 + cc;
                float v = acc[mi][ni][r];
                if (OUT_BF16)
                    ((u16*)Cout)[(size_t)grow * N + gcol] = f2bf(v);
                else
                    ((float*)Cout)[(size_t)grow * N + gcol] = v;
            }
#undef STAGE_A
#undef STAGE_B
#undef RD_A
#undef RD_B
#undef MFMA_PH
}

// ---------------------------------------------------------------------------
// 128x128 GEMM (C = A @ B^T), pipelined 128-tile for the thin out-proj
// (N=1024 -> 512 blocks). BK=64, 8 waves (2M x 4N), per-wave C = 64x32.
// LDS 64 KiB dbuf -> 2 blocks/CU (4 waves/SIMD).
// R10 change vs R6: bf1 read moved to the tile-end read group and the two
// 8-MFMA clusters merged under ONE lgkmcnt(0) (16 MFMA/cluster) -- halves
// the exposed LDS waits per tile. Barrier count/positions unchanged:
//   mid-BAR: reached by every wave after its lgkm0 (all buf[cur] B reads
//            drained) -> STAGE_B(CUR) after it is WAR-safe (same as R6).
//   end-BAR: preceded by vmcnt(2) (newest 2 = B(t+2) => A(t+1),B(t+1)
//            landed) -> tile-end reads of buf[nxt] safe (same as R6).
// Live-set: bf0+bf1 both live across the cluster = +8 VGPR over R6 (kernel
// has only 32 acc VGPRs -- fits the 128 cap at 4 waves/SIMD).
// Stage pointers overrun K-end by <=2 tiles into the following allocation
// (ysk->float bufs, owb->wsb; both readable), landing in a dead LDS buffer.
// ---------------------------------------------------------------------------
template <int OUT_BF16>
__global__ __launch_bounds__(512, 4) void gemm_bt_128p(
    const u16* __restrict__ A, const u16* __restrict__ B,
    void* __restrict__ Cout, int N, int K) {
    __shared__ u16 sAf[2 * 128 * 64];   // [buf][row*64 + slot*8]
    __shared__ u16 sBf[2 * 128 * 64];
    const int tid = threadIdx.x;
    const int lane = tid & 63;
    const int wave = tid >> 6;   // 0..7
    const int wm = wave >> 2;    // 0..1  (M half: 64 rows)
    const int wn = wave & 3;     // 0..3  (N quarter: 32 cols)

    const int gx = gridDim.x;
    const int nwg = gx * gridDim.y;
    const int cpx = nwg >> 3;                       // nwg % 8 == 0 here
    int lin = blockIdx.y * gx + blockIdx.x;
    int swz = (lin & 7) * cpx + (lin >> 3);
    const int bm = (swz / gx) * 128;
    const int bn = (swz % gx) * 128;

    const int gslot = (lane & 7) ^ ((lane >> 3) & 7);
    const int srowoff = lane >> 3;                  // 0..7
    const u16* aStage = A + (size_t)(bm + wave * 8 + srowoff) * K + gslot * 8 + 64;
    const u16* bStage = B + (size_t)(bn + wave * 8 + srowoff) * K + gslot * 8 + 128;
    const size_t row64 = (size_t)64 * K;

#define STAGE_A(BUF, PTR)                                                     \
    do {                                                                      \
        GL_LDS((PTR),         &sAf[(BUF) * 8192 + wave * 512]);               \
        GL_LDS((PTR) + row64, &sAf[(BUF) * 8192 + (8 + wave) * 512]);         \
    } while (0)
#define STAGE_B(BUF, PTR)                                                     \
    do {                                                                      \
        GL_LDS((PTR),         &sBf[(BUF) * 8192 + wave * 512]);               \
        GL_LDS((PTR) + row64, &sBf[(BUF) * 8192 + (8 + wave) * 512]);         \
    } while (0)

    const int fr = lane & 15;
    const int kq = lane >> 4;
    const int st0 = kq ^ (fr & 7);
    const int st1 = (4 + kq) ^ (fr & 7);
    const int aRd0 = (wm * 64 + fr) * 64 + st0 * 8;
    const int aRd1 = (wm * 64 + fr) * 64 + st1 * 8;
    const int bRd0 = (wn * 32 + fr) * 64 + st0 * 8;
    const int bRd1 = (wn * 32 + fr) * 64 + st1 * 8;

#define RD_A(dst, BUF)                                                        \
    do {                                                                      \
        _Pragma("unroll")                                                     \
        for (int mi = 0; mi < 4; ++mi) {                                      \
            dst[mi][0] = *(const short8*)&sAf[(BUF) * 8192 + aRd0 + mi * 16 * 64]; \
            dst[mi][1] = *(const short8*)&sAf[(BUF) * 8192 + aRd1 + mi * 16 * 64]; \
        }                                                                     \
    } while (0)
#define RD_B(dst, BUF, NI)                                                    \
    do {                                                                      \
        dst[0] = *(const short8*)&sBf[(BUF) * 8192 + bRd0 + (NI) * 16 * 64];  \
        dst[1] = *(const short8*)&sBf[(BUF) * 8192 + bRd1 + (NI) * 16 * 64];  \
    } while (0)
#define MFMA8(BF, NI)                                                         \
    do {                                                                      \
        _Pragma("unroll")                                                     \
        for (int kh = 0; kh < 2; ++kh)                                        \
            _Pragma("unroll")                                                 \
            for (int mi = 0; mi < 4; ++mi)                                    \
                acc[mi][NI] = __builtin_amdgcn_mfma_f32_16x16x32_bf16(        \
                    afc[mi][kh], BF[kh], acc[mi][NI], 0, 0, 0);               \
    } while (0)

    floatx4 acc[4][2];
#pragma unroll
    for (int i = 0; i < 4; ++i)
#pragma unroll
        for (int j = 0; j < 2; ++j) acc[i][j] = (floatx4){0.f, 0.f, 0.f, 0.f};

    short8 afc[4][2], bf0[2], bf1[2];

    STAGE_A(0, aStage - 64);
    STAGE_B(0, bStage - 128);
    STAGE_B(1, bStage - 64);
    VMC2();   // A(0),B(0) landed; B(1) in flight
    BAR();
    RD_A(afc, 0);
    RD_B(bf0, 0, 0);
    RD_B(bf1, 0, 1);
    SB0();

#define TILE(CUR, NXT)                                                        \
    /* single lgkm drains all tile-end reads; 16-MFMA cluster */              \
    LGKM0();                                                                  \
    PRIO1();                                                                  \
    MFMA8(bf0, 0);                                                            \
    MFMA8(bf1, 1);                                                            \
    PRIO0();                                                                  \
    SB0();                                                                    \
    STAGE_A(NXT, aStage);                                                     \
    BAR(); /* mid: all waves past lgkm0 -> buf[cur] B reads drained */        \
    STAGE_B(CUR, bStage);                                                     \
    VMC2(); /* A(t+1), B(t+1) landed; B(t+2) in flight */                     \
    BAR();                                                                    \
    RD_A(afc, NXT);                                                           \
    RD_B(bf0, NXT, 0);                                                        \
    RD_B(bf1, NXT, 1);                                                        \
    SB0();                                                                    \
    aStage += 64;                                                             \
    bStage += 64;

    const int NT = K >> 6;  // 32 here (even)
    for (int t = 0; t < NT; t += 2) {
        TILE(0, 1)
        TILE(1, 0)
    }
#undef TILE

    asm volatile("s_waitcnt vmcnt(0)" ::: "memory");  // drain overrun stages

    const int cc = lane & 15;
    const int rb = (lane >> 4) * 4;
#pragma unroll
    for (int mi = 0; mi < 4; ++mi)
#pragma unroll
        for (int ni = 0; ni < 2; ++ni)
#pragma unroll
            for (int r = 0; r < 4; ++r) {
                int grow = bm + wm * 64 + mi * 16 + rb + r;
                int gcol = bn + wn * 32 + ni * 16 + cc;
                float v = acc[mi][ni][r];
                if (OUT_BF16)
                    ((u16*)Cout)[(size_t)grow * N + gcol] = f2bf(v);
                else
                    ((float*)Cout)[(size_t)grow * N + gcol] = v;
            }
#undef STAGE_A
#undef STAGE_B
#undef RD_A
#undef RD_B
#undef MFMA8
}

// depthwise causal conv (DC=4) + bias + silu + row-mean. (R6 verbatim --
// the R9 LDS-fused conv_dbc cut occupancy to 2 blocks/CU and regressed.)
__global__ __launch_bounds__(256) void conv_silu_avg(
    const u16* __restrict__ xin, const float* __restrict__ cw,
    const float* __restrict__ cb, u16* __restrict__ xconv,
    float* __restrict__ xavg) {
    const int blk = blockIdx.x;        // 512 blocks
    const int b = blk >> 7;
    const int lc = blk & 127;
    const int row0 = b * LL + lc * 16;
    const int tid = threadIdx.x;
    const int lane = tid & 63, wave = tid >> 6;
    const int d0 = tid * 8;
    float4 cwv[8];
    float cbv[8];
#pragma unroll
    for (int e = 0; e < 8; ++e) cwv[e] = *(const float4*)&cw[(d0 + e) * 4];
#pragma unroll
    for (int e = 0; e < 8; e += 4) {
        float4 c = *(const float4*)&cb[d0 + e];
        cbv[e] = c.x; cbv[e + 1] = c.y; cbv[e + 2] = c.z; cbv[e + 3] = c.w;
    }
    u16x8 w0, w1, w2;
    if (lc == 0) {
        w0 = (u16x8)0; w1 = (u16x8)0; w2 = (u16x8)0;
    } else {
        w0 = *(const u16x8*)&xin[(size_t)(row0 - 3) * (2 * DINNER) + d0];
        w1 = *(const u16x8*)&xin[(size_t)(row0 - 2) * (2 * DINNER) + d0];
        w2 = *(const u16x8*)&xin[(size_t)(row0 - 1) * (2 * DINNER) + d0];
    }
    float sums[16];
#pragma unroll
    for (int t = 0; t < 16; ++t) {
        u16x8 cur = *(const u16x8*)&xin[(size_t)(row0 + t) * (2 * DINNER) + d0];
        float lsum = 0.f;
        u16x8 o;
#pragma unroll
        for (int e = 0; e < 8; ++e) {
            float acc = cbv[e];
            acc += bf2f(w0[e]) * cwv[e].x;
            acc += bf2f(w1[e]) * cwv[e].y;
            acc += bf2f(w2[e]) * cwv[e].z;
            acc += bf2f(cur[e]) * cwv[e].w;
            float s = silu_f(acc);
            lsum += s;
            o[e] = f2bf(s);
        }
        *(u16x8*)&xconv[(size_t)(row0 + t) * DINNER + d0] = o;
        sums[t] = lsum;
        w0 = w1; w1 = w2; w2 = cur;
    }
#pragma unroll
    for (int off = 32; off; off >>= 1)
#pragma unroll
        for (int t = 0; t < 16; ++t) sums[t] += __shfl_down(sums[t], off);
    __shared__ float wred[4][16];
    if (lane == 0) {
#pragma unroll
        for (int t = 0; t < 16; ++t) wred[wave][t] = sums[t];
    }
    __syncthreads();
    if (tid < 16)
        xavg[row0 + tid] = (wred[0][tid] + wred[1][tid] + wred[2][tid] + wred[3][tid]) *
                           (1.f / DINNER);
}

// delta/B/C projections: thin GEMM (8192 x 48 x 2048), K split across waves.
// (R6 verbatim.)
__global__ __launch_bounds__(256) void dbc_direct(
    const u16* __restrict__ xconv, const u16* __restrict__ wcat,
    const float* __restrict__ db, const float* __restrict__ A_log,
    const float* __restrict__ xavg,
    float* __restrict__ a_out, float* __restrict__ u_out, float* __restrict__ c_out) {
    __shared__ float part[4][32][48];
    const int tid = threadIdx.x;
    const int lane = tid & 63;
    const int wave = tid >> 6;
    const int bm = blockIdx.x * 32;
    const int fr = lane & 15;
    const int kq = lane >> 4;
    const int k0 = wave * 512 + kq * 8;

    const u16* ap0 = xconv + (size_t)(bm + fr) * DINNER + k0;
    const u16* ap1 = xconv + (size_t)(bm + 16 + fr) * DINNER + k0;
    const u16* bp0 = wcat + (size_t)(fr) * DINNER + k0;
    const u16* bp1 = wcat + (size_t)(16 + fr) * DINNER + k0;
    const u16* bp2 = wcat + (size_t)(32 + fr) * DINNER + k0;

    floatx4 acc[2][3];
#pragma unroll
    for (int mi = 0; mi < 2; ++mi)
#pragma unroll
        for (int ni = 0; ni < 3; ++ni) acc[mi][ni] = (floatx4){0.f, 0.f, 0.f, 0.f};

#pragma unroll 4
    for (int kk = 0; kk < 16; ++kk) {
        short8 a0 = *(const short8*)ap0;
        short8 a1 = *(const short8*)ap1;
        short8 b0 = *(const short8*)bp0;
        short8 b1 = *(const short8*)bp1;
        short8 b2 = *(const short8*)bp2;
        ap0 += 32; ap1 += 32; bp0 += 32; bp1 += 32; bp2 += 32;
        acc[0][0] = __builtin_amdgcn_mfma_f32_16x16x32_bf16(a0, b0, acc[0][0], 0, 0, 0);
        acc[0][1] = __builtin_amdgcn_mfma_f32_16x16x32_bf16(a0, b1, acc[0][1], 0, 0, 0);
        acc[0][2] = __builtin_amdgcn_mfma_f32_16x16x32_bf16(a0, b2, acc[0][2], 0, 0, 0);
        acc[1][0] = __builtin_amdgcn_mfma_f32_16x16x32_bf16(a1, b0, acc[1][0], 0, 0, 0);
        acc[1][1] = __builtin_amdgcn_mfma_f32_16x16x32_bf16(a1, b1, acc[1][1], 0, 0, 0);
        acc[1][2] = __builtin_amdgcn_mfma_f32_16x16x32_bf16(a1, b2, acc[1][2], 0, 0, 0);
    }
    // C/D 16x16 layout: col = lane&15, row = (lane>>4)*4 + r
    const int cr = kq * 4;
#pragma unroll
    for (int mi = 0; mi < 2; ++mi)
#pragma unroll
        for (int ni = 0; ni < 3; ++ni)
#pragma unroll
            for (int r = 0; r < 4; ++r)
                part[wave][mi * 16 + cr + r][ni * 16 + fr] = acc[mi][ni][r];
    __syncthreads();
#pragma unroll
    for (int it = tid; it < 512; it += 256) {
        int row = it >> 4;
        int s = it & 15;
        float sd = 0.f, sb = 0.f, sc = 0.f;
#pragma unroll
        for (int w = 0; w < 4; ++w) {
            sd += part[w][row][s];
            sb += part[w][row][s + 16];
            sc += part[w][row][s + 32];
        }
        int grow = bm + row;
        float Aa = -__expf(A_log[s]);
        float pre = sd + db[s];
        float delta = (pre > 20.f) ? pre : log1pf(__expf(pre));
        a_out[grow * NSTATE + s] = __expf(delta * Aa);
        u_out[grow * NSTATE + s] = delta * sb * xavg[grow];
        c_out[grow * NSTATE + s] = sc;
    }
}

// ---- fused parallel linear scan: one kernel, 4 blocks (one per batch) ----
__global__ __launch_bounds__(1024) void scan_fused(
    const float* __restrict__ a, const float* __restrict__ u,
    const float* __restrict__ c, float* __restrict__ y) {
    const int b = blockIdx.x;
    const int tid = threadIdx.x;
    const int s = tid & 15;
    const int seg = tid >> 4;   // 0..63
    __shared__ float Ps[NSEG][NSTATE];
    __shared__ float Hs[NSEG][NSTATE];
    __shared__ float HSs[NSEG][NSTATE];

    size_t base = (size_t)(b * LL + seg * SEGLEN) * NSTATE + s;
    float P = 1.f, h = 0.f;
#pragma unroll 8
    for (int t = 0; t < SEGLEN; ++t) {
        float av = a[base + (size_t)t * NSTATE];
        float uv = u[base + (size_t)t * NSTATE];
        h = fmaf(av, h, uv);
        P *= av;
    }
    Ps[seg][s] = P;
    Hs[seg][s] = h;
    __syncthreads();
    if (tid < 16) {
        float hh = 0.f;
        for (int g = 0; g < NSEG; ++g) {
            HSs[g][tid] = hh;
            hh = fmaf(Ps[g][tid], hh, Hs[g][tid]);
        }
    }
    __syncthreads();
    float h2 = HSs[seg][s];
#pragma unroll 8
    for (int t = 0; t < SEGLEN; ++t) {
        float av = a[base + (size_t)t * NSTATE];
        float uv = u[base + (size_t)t * NSTATE];
        float cv = c[base + (size_t)t * NSTATE];
        h2 = fmaf(av, h2, uv);
        float p = h2 * cv;
        p += __shfl_xor(p, 1);
        p += __shfl_xor(p, 2);
        p += __shfl_xor(p, 4);
        p += __shfl_xor(p, 8);
        if (s == 0) y[b * LL + seg * SEGLEN + t] = p;
    }
}

// y_skip = y*silu(x_gate) + x_conv*D  -> bf16
__global__ __launch_bounds__(256) void gate_skip(
    const u16* __restrict__ xin, const float* __restrict__ y,
    const float* __restrict__ Dv, const u16* __restrict__ xconv,
    u16* __restrict__ yskip) {
    size_t i = ((size_t)blockIdx.x * 256 + threadIdx.x) * 8;
    int row = (int)(i >> 11);
    int d = (int)(i & (DINNER - 1));
    u16x8 g = *(const u16x8*)&xin[(size_t)row * (2 * DINNER) + DINNER + d];
    u16x8 xc = *(const u16x8*)&xconv[i];
    float yv = y[row];
    u16x8 o;
#pragma unroll
    for (int e = 0; e < 8; ++e) {
        float gv = silu_f(bf2f(g[e]));
        float v = yv * gv + bf2f(xc[e]) * Dv[d + e];
        o[e] = f2bf(v);
    }
    *(u16x8*)&yskip[i] = o;
}

extern "C" void kernel_launch(void* const* d_in, const int* in_sizes, int n_in,
                              void* d_out, int out_size, void* d_ws, size_t ws_size,
                              hipStream_t stream) {
    const float* x       = (const float*)d_in[0];
    const float* w_in    = (const float*)d_in[1];
    const float* conv_w  = (const float*)d_in[2];
    const float* conv_b  = (const float*)d_in[3];
    const float* A_log   = (const float*)d_in[4];
    const float* Dv      = (const float*)d_in[5];
    const float* delta_w = (const float*)d_in[6];
    const float* delta_b = (const float*)d_in[7];
    const float* B_w     = (const float*)d_in[8];
    const float* C_w     = (const float*)d_in[9];
    const float* out_w   = (const float*)d_in[10];
    float* out = (float*)d_out;

    u16* xb  = (u16*)d_ws;                 // 8192*1024
    u16* wb  = xb + 8388608;               // 4096*1024
    u16* owb = wb + 4194304;               // 1024*2048
    u16* wsb = owb + 2097152;              // 48*2048 (concat dw,bw,cw)
    u16* xin = wsb + 98304;                // 8192*4096
    u16* xcv = xin + 33554432;             // 8192*2048
    u16* ysk = xcv + 16777216;             // 8192*2048
    float* fb     = (float*)(ysk + 16777216);
    float* abuf   = fb;                    // 8192*16
    float* ubuf   = abuf + 131072;
    float* cbuf   = ubuf + 131072;
    float* ybuf   = cbuf + 131072;         // 8192
    float* avgbuf = ybuf + 8192;           // 8192

    cvt_multi<<<7216, 256, 0, stream>>>(x, w_in, out_w, delta_w, B_w, C_w,
                                        xb, wb, owb, wsb, wsb + 32768, wsb + 65536);

    // x_inner = x @ in_proj_w.T : (8192x1024)@(4096x1024)^T -> bf16
    gemm_bt_256<1><<<dim3(16, 32), 512, 0, stream>>>(xb, wb, xin, 2 * DINNER, DMODEL);

    conv_silu_avg<<<512, 256, 0, stream>>>(xin, conv_w, conv_b, xcv, avgbuf);
    dbc_direct<<<256, 256, 0, stream>>>(xcv, wsb, delta_b, A_log, avgbuf,
                                        abuf, ubuf, cbuf);

    scan_fused<<<4, 1024, 0, stream>>>(abuf, ubuf, cbuf, ybuf);

    gate_skip<<<NROW * DINNER / 8 / 256, 256, 0, stream>>>(xin, ybuf, Dv, xcv, ysk);

    // out = y_skip @ out_proj_w.T : (8192x2048)@(1024x2048)^T -> fp32
    gemm_bt_128p<0><<<dim3(8, 64), 512, 0, stream>>>(ysk, owb, out, DMODEL, DINNER);
}